// Round 4
// baseline (1428.885 us; speedup 1.0000x reference)
//
#include <hip/hip_runtime.h>
#include <math.h>

#define N_TOK 32768
#define DDIM  512
#define KCODE 1024
#define DECAYF 0.99f
#define EPSV 1e-5f
#define CCOST 0.25f
#define MARGIN 0.05f   // hi-only bf16 dist err std ~2e-3 (worst ~4e-3); 0.05 = 8-12 sigma

typedef float f32x4 __attribute__((ext_vector_type(4)));
typedef short short8v __attribute__((ext_vector_type(8)));

// ---- bf16 helpers (RTN-even) ----
__device__ __forceinline__ unsigned short f2bf(float f) {
  unsigned u = __float_as_uint(f);
  u += 0x7fffu + ((u >> 16) & 1u);
  return (unsigned short)(u >> 16);
}
__device__ __forceinline__ float bf2f(unsigned short h) {
  return __uint_as_float(((unsigned)h) << 16);
}

// ---- monotone float<->ordered-uint for argmin key packing ----
__device__ __forceinline__ unsigned ordf(float f) {
  unsigned u = __float_as_uint(f);
  return (u & 0x80000000u) ? ~u : (u | 0x80000000u);
}
__device__ __forceinline__ float ord2f(unsigned v) {
  unsigned u = (v & 0x80000000u) ? (v & 0x7fffffffu) : ~v;
  return __uint_as_float(u);
}
__device__ __forceinline__ void top2m(unsigned long long& a1, unsigned long long& a2,
                                      unsigned long long b1, unsigned long long b2) {
  unsigned long long m1 = a1 < b1 ? a1 : b1;
  unsigned long long hi = a1 < b1 ? b1 : a1;
  unsigned long long m2 = a2 < b2 ? a2 : b2;
  a2 = m2 < hi ? m2 : hi;
  a1 = m1;
}

// ---- async global->LDS, 16B/lane ----
__device__ __forceinline__ void stage16(const void* g, char* lds_base, int lane) {
#if __has_builtin(__builtin_amdgcn_global_load_lds)
  __builtin_amdgcn_global_load_lds((const __attribute__((address_space(1))) void*)g,
                                   (__attribute__((address_space(3))) void*)lds_base,
                                   16, 0, 0);
#else
  *(float4*)(lds_base + lane * 16) = *(const float4*)g;
#endif
}

// ---------------- fused conversion: x and w -> bf16 hi, + w fp64 norms ----------------
// R8: hi-only pipeline — xlo/wlo dropped (refine + MARGIN absorb the precision gap).
__global__ __launch_bounds__(256) void convert_fused(
    const float* __restrict__ x, const float* __restrict__ w,
    unsigned short* __restrict__ xhi, unsigned short* __restrict__ whi,
    float* __restrict__ wn)
{
  int b = blockIdx.x;
  int tid = threadIdx.x;
  if (b < 16384) {              // x part: 16384 blocks x 256 thr x float4
    size_t i = (size_t)b * 256 + tid;
    float4 v = *(const float4*)(x + i * 4);
    ushort4 h;
    h.x = f2bf(v.x);
    h.y = f2bf(v.y);
    h.z = f2bf(v.z);
    h.w = f2bf(v.w);
    *(ushort4*)(xhi + i * 4) = h;
  } else {                      // w part: 256 blocks, each wave handles one row
    int k = (b - 16384) * 4 + (tid >> 6);
    int lane = tid & 63;
    double s = 0.0;
    #pragma unroll
    for (int it = 0; it < 2; it++) {
      size_t off = (size_t)k * DDIM + (lane + 64 * it) * 4;
      float4 v = *(const float4*)(w + off);
      s += (double)v.x*(double)v.x + (double)v.y*(double)v.y
         + (double)v.z*(double)v.z + (double)v.w*(double)v.w;
      ushort4 h;
      h.x = f2bf(v.x);
      h.y = f2bf(v.y);
      h.z = f2bf(v.z);
      h.w = f2bf(v.w);
      *(ushort4*)(whi + off) = h;
    }
    for (int o = 32; o > 0; o >>= 1) s += __shfl_down(s, o, 64);
    if (lane == 0) wn[k] = (float)s;
  }
}

// ---------------- MFMA distance + top-2 argmin ----------------
// R8: revert to the R5/122us-verified single-buffer 2-barrier structure
// (R2/R3 dbuf experiments both regressed: 64KB LDS occupancy loss > pipeline
// gain). hi*hi pass only -> 1/3 MFMA + staging, 16KB LDS -> more blocks/CU.
// XOR slot-swizzle (0 bank conflicts, R1-verified) + XCD remap kept.
__global__ __launch_bounds__(256) void dist_mfma(
    const unsigned short* __restrict__ xhi, const unsigned short* __restrict__ whi,
    const float* __restrict__ wn,
    unsigned long long* __restrict__ k1buf, unsigned long long* __restrict__ k2buf)
{
  __shared__ __align__(16) short sA[128 * 32];
  __shared__ __align__(16) short sB[128 * 32];
  const int tid = threadIdx.x;
  const int wv = tid >> 6, lane = tid & 63;
  // XCD-aware bijective remap: 2048 blocks % 8 XCDs == 0 -> contiguous
  // 256-block chunk per XCD; the 8 kb-strips of one tb share A-tiles in L2.
  const int wg = (blockIdx.x & 7) * 256 + (blockIdx.x >> 3);
  const int tb = wg >> 3, kb = wg & 7;
  const int row0 = tb * 128, col0 = kb * 128;
  const int rw = wv & 1, cw = wv >> 1;
  const int q = lane >> 4, cl = lane & 15;
  const int swz = (cl >> 1) & 3;          // == ((rl>>1)&3) for every frag row

  f32x4 acc[4][4];
  #pragma unroll
  for (int mt = 0; mt < 4; mt++)
    #pragma unroll
    for (int nt = 0; nt < 4; nt++) acc[mt][nt] = (f32x4){0.f, 0.f, 0.f, 0.f};

  // staging source geometry: lane l of chunk c writes LDS row r=(c*64+l)>>2,
  // physical slot p=l&3 (linear, global_load_lds requirement). Physical slot
  // p holds LOGICAL slot p ^ ((r>>1)&3) by fetching the swizzled source col.
  const int cA0 = wv * 64 + lane;
  const int r0 = cA0 >> 2;
  const int s0 = (cA0 & 3) ^ ((r0 >> 1) & 3);
  const size_t aoff0 = (size_t)(row0 + r0) * 1024 + (size_t)s0 * 16;
  const size_t boff0 = (size_t)(col0 + r0) * 1024 + (size_t)s0 * 16;
  const char* pxh = (const char*)xhi;
  const char* pwh = (const char*)whi;

  // LDS read bases: logical (row rl, slot q) lives at physical slot q^swz.
  const int aidx = (rw * 64 + cl) * 32 + (q ^ swz) * 8;
  const int bidx = (cw * 64 + cl) * 32 + (q ^ swz) * 8;

  for (int ks = 0; ks < 16; ks++) {
    const int k2 = ks * 64;   // byte offset of this 32-short k-slice
    __syncthreads();
    stage16(pxh + aoff0 + k2,         (char*)sA + wv * 1024, lane);
    stage16(pxh + aoff0 + 65536 + k2, (char*)sA + (wv + 4) * 1024, lane);
    stage16(pwh + boff0 + k2,         (char*)sB + wv * 1024, lane);
    stage16(pwh + boff0 + 65536 + k2, (char*)sB + (wv + 4) * 1024, lane);
    __syncthreads();

    short8v a[4], b[4];
    #pragma unroll
    for (int mt = 0; mt < 4; mt++) a[mt] = *(const short8v*)(sA + aidx + mt * 512);
    #pragma unroll
    for (int nt = 0; nt < 4; nt++) b[nt] = *(const short8v*)(sB + bidx + nt * 512);
    #pragma unroll
    for (int mt = 0; mt < 4; mt++)
      #pragma unroll
      for (int nt = 0; nt < 4; nt++)
        acc[mt][nt] = __builtin_amdgcn_mfma_f32_16x16x32_bf16(a[mt], b[nt], acc[mt][nt], 0, 0, 0);
  }

  float wnv[4];
  #pragma unroll
  for (int nt = 0; nt < 4; nt++) wnv[nt] = wn[col0 + cw * 64 + nt * 16 + cl];

  const int strip = kb * 2 + cw;
  #pragma unroll
  for (int mt = 0; mt < 4; mt++) {
    #pragma unroll
    for (int r = 0; r < 4; r++) {
      unsigned long long k1 = ~0ull, k2 = ~0ull;
      #pragma unroll
      for (int nt = 0; nt < 4; nt++) {
        int kk = col0 + cw * 64 + nt * 16 + cl;
        float dist = fmaf(-2.f, acc[mt][nt][r], wnv[nt]);
        unsigned long long key = (kk == 0) ? ~0ull
            : ((unsigned long long)ordf(dist) << 32) | (unsigned)kk;
        if (key < k1) { k2 = k1; k1 = key; }
        else if (key < k2) k2 = key;
      }
      #pragma unroll
      for (int off = 8; off > 0; off >>= 1) {
        unsigned long long o1 = __shfl_down(k1, off, 16);
        unsigned long long o2 = __shfl_down(k2, off, 16);
        top2m(k1, k2, o1, o2);
      }
      if (cl == 0) {
        int rowg = row0 + rw * 64 + mt * 16 + q * 4 + r;
        k1buf[strip * N_TOK + rowg] = k1;
        k2buf[strip * N_TOK + rowg] = k2;
      }
    }
  }
}

// ---------------- merge strips + pad mask + margin flag + LDS histogram ----------------
__global__ __launch_bounds__(1024) void combine_kernel(
    const unsigned long long* __restrict__ k1buf, const unsigned long long* __restrict__ k2buf,
    const int* __restrict__ mask,
    int* __restrict__ idx_i, int* __restrict__ flagList, int* __restrict__ flagcnt,
    int* __restrict__ counts_i)
{
  __shared__ int lh[KCODE];
  int tid = threadIdx.x;
  lh[tid] = 0;
  __syncthreads();
  int t = blockIdx.x * 1024 + tid;
  unsigned long long a1 = ~0ull, a2 = ~0ull;
  #pragma unroll
  for (int s = 0; s < 16; s++)
    top2m(a1, a2, k1buf[s * N_TOK + t], k2buf[s * N_TOK + t]);
  int bi = (int)(a1 & 0xffffffffu);
  float d1 = ord2f((unsigned)(a1 >> 32));
  float d2 = ord2f((unsigned)(a2 >> 32));
  int pad = mask[t];
  int id = pad ? 0 : bi;
  idx_i[t] = id;
  atomicAdd(&lh[id], 1);
  if (!pad && (d2 - d1) < MARGIN) {
    int p = atomicAdd(flagcnt, 1);
    flagList[p] = t;
  }
  __syncthreads();
  if (lh[tid] > 0) atomicAdd(&counts_i[tid], lh[tid]);
}

// ---------------- numpy-f32-emulating re-check + counts patch ----------------
__global__ __launch_bounds__(256) void refine_kernel(
    const float* __restrict__ x, const float* __restrict__ w,
    const float* __restrict__ wn32,
    const int* __restrict__ flagList, const int* __restrict__ flagcnt,
    int* __restrict__ idx_i, int* __restrict__ counts_i)
{
  __shared__ double xd[DDIM];
  __shared__ double redbuf[4];
  __shared__ float A32sh;
  __shared__ float bv_s[256];
  __shared__ int   bi_s[256];
  int tid = threadIdx.x;
  int lane = tid & 63, wid = tid >> 6;
  int nf = *flagcnt;
  for (int fi = blockIdx.x; fi < nf; fi += gridDim.x) {
    int token = flagList[fi];
    double part = 0.0;
    for (int e = tid; e < DDIM; e += 256) {
      double v = (double)x[(size_t)token * DDIM + e];
      xd[e] = v;
      part += v * v;
    }
    for (int o = 32; o > 0; o >>= 1) part += __shfl_down(part, o, 64);
    if (lane == 0) redbuf[wid] = part;
    __syncthreads();
    if (tid == 0) {
      double a64 = redbuf[0] + redbuf[1] + redbuf[2] + redbuf[3];
      A32sh = (float)a64;
    }
    __syncthreads();
    float A32 = A32sh;
    float bv = 3.4e38f; int bi = 0x7fffffff;
    for (int k = tid; k < KCODE; k += 256) {
      if (k == 0) continue;
      const float4* wr = (const float4*)(w + (size_t)k * DDIM);
      double dot = 0.0;
      #pragma unroll 4
      for (int dq = 0; dq < DDIM / 4; dq++) {
        float4 wv = wr[dq];
        dot += xd[dq*4+0]*(double)wv.x + xd[dq*4+1]*(double)wv.y
             + xd[dq*4+2]*(double)wv.z + xd[dq*4+3]*(double)wv.w;
      }
      float M = (float)dot;
      float AB = A32 + wn32[k];
      float dist = AB - 2.0f * M;
      if (dist < bv) { bv = dist; bi = k; }
    }
    bv_s[tid] = bv; bi_s[tid] = bi;
    __syncthreads();
    for (int st = 128; st > 0; st >>= 1) {
      if (tid < st) {
        if (bv_s[tid+st] < bv_s[tid] ||
            (bv_s[tid+st] == bv_s[tid] && bi_s[tid+st] < bi_s[tid])) {
          bv_s[tid] = bv_s[tid+st]; bi_s[tid] = bi_s[tid+st];
        }
      }
      __syncthreads();
    }
    if (tid == 0) {
      int old = idx_i[token];
      int nw = bi_s[0];
      if (nw != old) {
        idx_i[token] = nw;
        atomicSub(&counts_i[old], 1);
        atomicAdd(&counts_i[nw], 1);
      }
    }
    __syncthreads();
  }
}

// ---------------- exclusive scan of counts ----------------
__global__ __launch_bounds__(1024) void scan_kernel(
    const int* __restrict__ counts_i, int* __restrict__ offsets, int* __restrict__ cursor)
{
  __shared__ int tmp[1024];
  int t = threadIdx.x;
  int c = counts_i[t];
  tmp[t] = c;
  __syncthreads();
  for (int off = 1; off < 1024; off <<= 1) {
    int v = (t >= off) ? tmp[t - off] : 0;
    __syncthreads();
    tmp[t] += v;
    __syncthreads();
  }
  int ex = tmp[t] - c;
  offsets[t] = ex;
  cursor[t] = ex;
}

// ---------------- scatter with LDS rank aggregation ----------------
__global__ __launch_bounds__(1024) void scatter_kernel(
    const int* __restrict__ idx_i, int* __restrict__ cursor, int* __restrict__ bucket)
{
  __shared__ int lh[KCODE];
  __shared__ int lb[KCODE];
  int tid = threadIdx.x;
  lh[tid] = 0;
  __syncthreads();
  int token = blockIdx.x * 1024 + tid;
  int id = idx_i[token];
  int r = atomicAdd(&lh[id], 1);
  __syncthreads();
  if (lh[tid] > 0) lb[tid] = atomicAdd(&cursor[tid], lh[tid]);
  __syncthreads();
  bucket[lb[id] + r] = token;
}

// ---------------- quantized output + out_idx + loss ----------------
__global__ __launch_bounds__(256) void quant_kernel(
    const float* __restrict__ x, const float* __restrict__ w,
    const int* __restrict__ idx_i,
    float* __restrict__ out_q, float* __restrict__ out_idx, float* __restrict__ losssum)
{
  __shared__ float sred[4];
  int tid = threadIdx.x;
  int qd = tid & 127, h = tid >> 7;
  float s = 0.f;
  #pragma unroll
  for (int i = 0; i < 8; i++) {
    int token = blockIdx.x * 16 + i * 2 + h;
    int idx = idx_i[token];
    float4 xv = *(const float4*)(x + (size_t)token * DDIM + qd * 4);
    float4 wv = *(const float4*)(w + (size_t)idx * DDIM + qd * 4);
    *(float4*)(out_q + (size_t)token * DDIM + qd * 4) = wv;
    if (qd == 0) out_idx[token] = (float)idx;
    float dx = wv.x - xv.x, dy = wv.y - xv.y, dz = wv.z - xv.z, dww = wv.w - xv.w;
    s += dx*dx + dy*dy + dz*dz + dww*dww;
  }
  for (int o = 32; o > 0; o >>= 1) s += __shfl_down(s, o, 64);
  int lane = tid & 63, wid = tid >> 6;
  if (lane == 0) sred[wid] = s;
  __syncthreads();
  if (tid == 0) atomicAdd(losssum, sred[0] + sred[1] + sred[2] + sred[3]);
}

// ---------------- dw: balanced contiguous bucket ranges, run-flush atomics ----------------
__global__ __launch_bounds__(128) void dw_kernel(
    const float* __restrict__ x, const int* __restrict__ bucket,
    const int* __restrict__ idx_i, float* __restrict__ dw)
{
  int b0 = blockIdx.x * 32;
  int t = threadIdx.x;
  // per-lane: entry (t&31); broadcast via shuffle in the loop
  int ent = bucket[b0 + (t & 31)];
  int eid = idx_i[ent];
  int tok0 = __shfl(ent, 0, 64);
  int cur  = __shfl(eid, 0, 64);
  float4 acc = make_float4(0.f, 0.f, 0.f, 0.f);
  float4 nv = *(const float4*)(x + (size_t)tok0 * DDIM + t * 4);
  for (int j = 0; j < 32; j++) {
    float4 v = nv;
    int id = __shfl(eid, j, 64);
    if (j < 31) {
      int tn = __shfl(ent, j + 1, 64);
      nv = *(const float4*)(x + (size_t)tn * DDIM + t * 4);
    }
    if (id != cur) {   // wave-uniform branch
      float* p = dw + (size_t)cur * DDIM + t * 4;
      atomicAdd(p + 0, acc.x); atomicAdd(p + 1, acc.y);
      atomicAdd(p + 2, acc.z); atomicAdd(p + 3, acc.w);
      acc = make_float4(0.f, 0.f, 0.f, 0.f);
      cur = id;
    }
    acc.x += v.x; acc.y += v.y; acc.z += v.z; acc.w += v.w;
  }
  float* p = dw + (size_t)cur * DDIM + t * 4;
  atomicAdd(p + 0, acc.x); atomicAdd(p + 1, acc.y);
  atomicAdd(p + 2, acc.z); atomicAdd(p + 3, acc.w);
}

// ---------------- cs / loss / perplexity ----------------
__global__ __launch_bounds__(1024) void stats_kernel(
    const int* __restrict__ counts_i, const float* __restrict__ ema_cs,
    const float* __restrict__ losssum,
    float* __restrict__ out_loss, float* __restrict__ out_perp,
    float* __restrict__ out_cs)
{
  __shared__ float sbuf[17];
  int k = threadIdx.x;
  float cnt = (float)counts_i[k];
  float csr = ema_cs[k] * DECAYF + (1.f - DECAYF) * cnt;
  float v = csr;
  for (int o = 32; o > 0; o >>= 1) v += __shfl_down(v, o, 64);
  int lane = k & 63, wid = k >> 6;
  if (lane == 0) sbuf[wid] = v;
  __syncthreads();
  if (k == 0) { float n = 0.f; for (int i = 0; i < 16; i++) n += sbuf[i]; sbuf[16] = n; }
  __syncthreads();
  float n = sbuf[16];
  out_cs[k] = (csr + EPSV) / (n + (float)KCODE * EPSV) * n;
  __syncthreads();
  float p = cnt / (float)N_TOK;
  v = p * logf(p + 1e-10f);
  for (int o = 32; o > 0; o >>= 1) v += __shfl_down(v, o, 64);
  if (lane == 0) sbuf[wid] = v;
  __syncthreads();
  if (k == 0) {
    float s = 0.f; for (int i = 0; i < 16; i++) s += sbuf[i];
    out_perp[0] = expf(-s);
    float nonpad = (float)(N_TOK - counts_i[0]);
    out_loss[0] = CCOST * losssum[0] / (nonpad * (float)DDIM);
  }
}

// ---------------- EMA update + new codebook ----------------
__global__ __launch_bounds__(256) void ema_kernel(
    const float* __restrict__ ema_w, const float* __restrict__ dw,
    const float* __restrict__ cs,
    float* __restrict__ out_ema, float* __restrict__ out_cb)
{
  int i = blockIdx.x * 256 + threadIdx.x;
  int e = i * 4;
  int k = e >> 9;
  float4 dv = *(const float4*)(dw + e);
  float4 ew = *(const float4*)(ema_w + e);
  float4 ne;
  ne.x = ew.x * DECAYF + (1.f - DECAYF) * dv.x;
  ne.y = ew.y * DECAYF + (1.f - DECAYF) * dv.y;
  ne.z = ew.z * DECAYF + (1.f - DECAYF) * dv.z;
  ne.w = ew.w * DECAYF + (1.f - DECAYF) * dv.w;
  *(float4*)(out_ema + e) = ne;
  float4 cb;
  if (k == 0) { cb.x = 0.f; cb.y = 0.f; cb.z = 0.f; cb.w = 0.f; }
  else {
    float csk = cs[k];
    cb.x = ne.x / csk; cb.y = ne.y / csk; cb.z = ne.z / csk; cb.w = ne.w / csk;
  }
  *(float4*)(out_cb + e) = cb;
}

extern "C" void kernel_launch(void* const* d_in, const int* in_sizes, int n_in,
                              void* d_out, int out_size, void* d_ws, size_t ws_size,
                              hipStream_t stream) {
  const float* x      = (const float*)d_in[0];
  const int*   mask   = (const int*)d_in[1];
  const float* w      = (const float*)d_in[2];
  const float* ema_cs = (const float*)d_in[3];
  const float* ema_w  = (const float*)d_in[4];
  float* out = (float*)d_out;

  float* out_q    = out;                  // 16777216  quantized_st
  float* out_idx  = out + 16777216;       // 32768     idx (as float)
  float* out_loss = out + 16809984;       // 1
  float* out_perp = out + 16809985;       // 1
  float* out_cs   = out + 16809986;       // 1024
  float* out_ema  = out + 16811010;       // 524288
  float* out_cb   = out + 17335298;       // 524288

  // xhi lives in the (dead until quant) out_q region: 32 MB
  unsigned short* xhi = (unsigned short*)out_q;

  char* ws = (char*)d_ws;
  int*   counts_i = (int*)  (ws + 0);          // 4 KB   (zeroed)
  float* dw       = (float*)(ws + 4096);       // 2 MB   (zeroed)
  float* losssum  = (float*)(ws + 2101248);    // 4 B    (zeroed)
  int*   flagcnt  = (int*)  (ws + 2101252);    // 4 B    (zeroed)
  int*   offsets  = (int*)  (ws + 2101312);    // 4 KB
  int*   cursor   = (int*)  (ws + 2105408);    // 4 KB
  float* wn       = (float*)(ws + 2109504);    // 4 KB
  int*   idx_i    = (int*)  (ws + 2113600);    // 128 KB
  int*   bucket   = (int*)  (ws + 2244672);    // 128 KB
  unsigned short* whi = (unsigned short*)(ws + 2375744);   // 1 MB
  unsigned long long* k1buf = (unsigned long long*)(ws + 4472896);  // 4 MB
  unsigned long long* k2buf = (unsigned long long*)(ws + 8667200);  // 4 MB
  int*   flagList = (int*)  (ws + 12861504);   // 128 KB -> total ~13 MB

  hipMemsetAsync(ws, 0, 2101256, stream);  // counts + dw + losssum + flagcnt
  convert_fused<<<16384 + 256, 256, 0, stream>>>(x, w, xhi, whi, wn);
  dist_mfma<<<(N_TOK / 128) * 8, 256, 0, stream>>>(xhi, whi, wn, k1buf, k2buf);
  combine_kernel<<<N_TOK / 1024, 1024, 0, stream>>>(k1buf, k2buf, mask, idx_i, flagList, flagcnt, counts_i);
  refine_kernel<<<2048, 256, 0, stream>>>(x, w, wn, flagList, flagcnt, idx_i, counts_i);
  scan_kernel<<<1, 1024, 0, stream>>>(counts_i, offsets, cursor);
  scatter_kernel<<<N_TOK / 1024, 1024, 0, stream>>>(idx_i, cursor, bucket);
  quant_kernel<<<N_TOK / 16, 256, 0, stream>>>(x, w, idx_i, out_q, out_idx, losssum);
  dw_kernel<<<N_TOK / 32, 128, 0, stream>>>(x, bucket, idx_i, dw);
  stats_kernel<<<1, 1024, 0, stream>>>(counts_i, ema_cs, losssum, out_loss, out_perp, out_cs);
  ema_kernel<<<KCODE * DDIM / 4 / 256, 256, 0, stream>>>(ema_w, dw, out_cs, out_ema, out_cb);
}

// Round 6
// 487.695 us; speedup vs baseline: 2.9299x; 2.9299x over previous
//
#include <hip/hip_runtime.h>
#include <math.h>

#define N_TOK 32768
#define DDIM  512
#define KCODE 1024
#define DECAYF 0.99f
#define EPSV 1e-5f
#define CCOST 0.25f
#define MARGIN 0.02f   // hi-only dist-diff err std ~3.2e-3 -> 6 sigma; flags ~5% of tokens
#define RT 8           // refine: tokens per block batch

typedef float f32x4 __attribute__((ext_vector_type(4)));
typedef short short8v __attribute__((ext_vector_type(8)));

// ---- bf16 helpers (RTN-even) ----
__device__ __forceinline__ unsigned short f2bf(float f) {
  unsigned u = __float_as_uint(f);
  u += 0x7fffu + ((u >> 16) & 1u);
  return (unsigned short)(u >> 16);
}
__device__ __forceinline__ float bf2f(unsigned short h) {
  return __uint_as_float(((unsigned)h) << 16);
}

// ---- monotone float<->ordered-uint for argmin key packing ----
__device__ __forceinline__ unsigned ordf(float f) {
  unsigned u = __float_as_uint(f);
  return (u & 0x80000000u) ? ~u : (u | 0x80000000u);
}
__device__ __forceinline__ float ord2f(unsigned v) {
  unsigned u = (v & 0x80000000u) ? (v & 0x7fffffffu) : ~v;
  return __uint_as_float(u);
}
__device__ __forceinline__ void top2m(unsigned long long& a1, unsigned long long& a2,
                                      unsigned long long b1, unsigned long long b2) {
  unsigned long long m1 = a1 < b1 ? a1 : b1;
  unsigned long long hi = a1 < b1 ? b1 : a1;
  unsigned long long m2 = a2 < b2 ? a2 : b2;
  a2 = m2 < hi ? m2 : hi;
  a1 = m1;
}

// ---- async global->LDS, 16B/lane ----
__device__ __forceinline__ void stage16(const void* g, char* lds_base, int lane) {
#if __has_builtin(__builtin_amdgcn_global_load_lds)
  __builtin_amdgcn_global_load_lds((const __attribute__((address_space(1))) void*)g,
                                   (__attribute__((address_space(3))) void*)lds_base,
                                   16, 0, 0);
#else
  *(float4*)(lds_base + lane * 16) = *(const float4*)g;
#endif
}

// ---------------- fused conversion: x and w -> bf16 hi, + w fp64 norms ----------------
__global__ __launch_bounds__(256) void convert_fused(
    const float* __restrict__ x, const float* __restrict__ w,
    unsigned short* __restrict__ xhi, unsigned short* __restrict__ whi,
    float* __restrict__ wn)
{
  int b = blockIdx.x;
  int tid = threadIdx.x;
  if (b < 16384) {              // x part: 16384 blocks x 256 thr x float4
    size_t i = (size_t)b * 256 + tid;
    float4 v = *(const float4*)(x + i * 4);
    ushort4 h;
    h.x = f2bf(v.x);
    h.y = f2bf(v.y);
    h.z = f2bf(v.z);
    h.w = f2bf(v.w);
    *(ushort4*)(xhi + i * 4) = h;
  } else {                      // w part: 256 blocks, each wave handles one row
    int k = (b - 16384) * 4 + (tid >> 6);
    int lane = tid & 63;
    double s = 0.0;
    #pragma unroll
    for (int it = 0; it < 2; it++) {
      size_t off = (size_t)k * DDIM + (lane + 64 * it) * 4;
      float4 v = *(const float4*)(w + off);
      s += (double)v.x*(double)v.x + (double)v.y*(double)v.y
         + (double)v.z*(double)v.z + (double)v.w*(double)v.w;
      ushort4 h;
      h.x = f2bf(v.x);
      h.y = f2bf(v.y);
      h.z = f2bf(v.z);
      h.w = f2bf(v.w);
      *(ushort4*)(whi + off) = h;
    }
    for (int o = 32; o > 0; o >>= 1) s += __shfl_down(s, o, 64);
    if (lane == 0) wn[k] = (float)s;
  }
}

// ---------------- MFMA distance + top-2 argmin (R8 structure, unchanged) ----------------
__global__ __launch_bounds__(256) void dist_mfma(
    const unsigned short* __restrict__ xhi, const unsigned short* __restrict__ whi,
    const float* __restrict__ wn,
    unsigned long long* __restrict__ k1buf, unsigned long long* __restrict__ k2buf)
{
  __shared__ __align__(16) short sA[128 * 32];
  __shared__ __align__(16) short sB[128 * 32];
  const int tid = threadIdx.x;
  const int wv = tid >> 6, lane = tid & 63;
  const int wg = (blockIdx.x & 7) * 256 + (blockIdx.x >> 3);
  const int tb = wg >> 3, kb = wg & 7;
  const int row0 = tb * 128, col0 = kb * 128;
  const int rw = wv & 1, cw = wv >> 1;
  const int q = lane >> 4, cl = lane & 15;
  const int swz = (cl >> 1) & 3;

  f32x4 acc[4][4];
  #pragma unroll
  for (int mt = 0; mt < 4; mt++)
    #pragma unroll
    for (int nt = 0; nt < 4; nt++) acc[mt][nt] = (f32x4){0.f, 0.f, 0.f, 0.f};

  const int cA0 = wv * 64 + lane;
  const int r0 = cA0 >> 2;
  const int s0 = (cA0 & 3) ^ ((r0 >> 1) & 3);
  const size_t aoff0 = (size_t)(row0 + r0) * 1024 + (size_t)s0 * 16;
  const size_t boff0 = (size_t)(col0 + r0) * 1024 + (size_t)s0 * 16;
  const char* pxh = (const char*)xhi;
  const char* pwh = (const char*)whi;

  const int aidx = (rw * 64 + cl) * 32 + (q ^ swz) * 8;
  const int bidx = (cw * 64 + cl) * 32 + (q ^ swz) * 8;

  for (int ks = 0; ks < 16; ks++) {
    const int k2 = ks * 64;
    __syncthreads();
    stage16(pxh + aoff0 + k2,         (char*)sA + wv * 1024, lane);
    stage16(pxh + aoff0 + 65536 + k2, (char*)sA + (wv + 4) * 1024, lane);
    stage16(pwh + boff0 + k2,         (char*)sB + wv * 1024, lane);
    stage16(pwh + boff0 + 65536 + k2, (char*)sB + (wv + 4) * 1024, lane);
    __syncthreads();

    short8v a[4], b[4];
    #pragma unroll
    for (int mt = 0; mt < 4; mt++) a[mt] = *(const short8v*)(sA + aidx + mt * 512);
    #pragma unroll
    for (int nt = 0; nt < 4; nt++) b[nt] = *(const short8v*)(sB + bidx + nt * 512);
    #pragma unroll
    for (int mt = 0; mt < 4; mt++)
      #pragma unroll
      for (int nt = 0; nt < 4; nt++)
        acc[mt][nt] = __builtin_amdgcn_mfma_f32_16x16x32_bf16(a[mt], b[nt], acc[mt][nt], 0, 0, 0);
  }

  float wnv[4];
  #pragma unroll
  for (int nt = 0; nt < 4; nt++) wnv[nt] = wn[col0 + cw * 64 + nt * 16 + cl];

  const int strip = kb * 2 + cw;
  #pragma unroll
  for (int mt = 0; mt < 4; mt++) {
    #pragma unroll
    for (int r = 0; r < 4; r++) {
      unsigned long long k1 = ~0ull, k2 = ~0ull;
      #pragma unroll
      for (int nt = 0; nt < 4; nt++) {
        int kk = col0 + cw * 64 + nt * 16 + cl;
        float dist = fmaf(-2.f, acc[mt][nt][r], wnv[nt]);
        unsigned long long key = (kk == 0) ? ~0ull
            : ((unsigned long long)ordf(dist) << 32) | (unsigned)kk;
        if (key < k1) { k2 = k1; k1 = key; }
        else if (key < k2) k2 = key;
      }
      #pragma unroll
      for (int off = 8; off > 0; off >>= 1) {
        unsigned long long o1 = __shfl_down(k1, off, 16);
        unsigned long long o2 = __shfl_down(k2, off, 16);
        top2m(k1, k2, o1, o2);
      }
      if (cl == 0) {
        int rowg = row0 + rw * 64 + mt * 16 + q * 4 + r;
        k1buf[strip * N_TOK + rowg] = k1;
        k2buf[strip * N_TOK + rowg] = k2;
      }
    }
  }
}

// ---------------- merge strips + pad mask + margin flag + LDS histogram ----------------
__global__ __launch_bounds__(1024) void combine_kernel(
    const unsigned long long* __restrict__ k1buf, const unsigned long long* __restrict__ k2buf,
    const int* __restrict__ mask,
    int* __restrict__ idx_i, int* __restrict__ flagList, int* __restrict__ flagcnt,
    int* __restrict__ counts_i)
{
  __shared__ int lh[KCODE];
  int tid = threadIdx.x;
  lh[tid] = 0;
  __syncthreads();
  int t = blockIdx.x * 1024 + tid;
  unsigned long long a1 = ~0ull, a2 = ~0ull;
  #pragma unroll
  for (int s = 0; s < 16; s++)
    top2m(a1, a2, k1buf[s * N_TOK + t], k2buf[s * N_TOK + t]);
  int bi = (int)(a1 & 0xffffffffu);
  float d1 = ord2f((unsigned)(a1 >> 32));
  float d2 = ord2f((unsigned)(a2 >> 32));
  int pad = mask[t];
  int id = pad ? 0 : bi;
  idx_i[t] = id;
  atomicAdd(&lh[id], 1);
  if (!pad && (d2 - d1) < MARGIN) {
    int p = atomicAdd(flagcnt, 1);
    flagList[p] = t;
  }
  __syncthreads();
  if (lh[tid] > 0) atomicAdd(&counts_i[tid], lh[tid]);
}

// ---------------- batched exact re-check: RT tokens share one codebook sweep ----------------
// R9: refine was per-token-per-block -> nf x 2MB L2 streaming (1245us at nf~4K).
// Now each block stages RT=8 token rows in LDS (fp64) and every thread streams
// its 4 codes ONCE against all 8 tokens: 8x less w traffic, 8 independent fp64
// chains hide FMA latency. Numerics identical (fp64 dot -> f32, A32+wn-2M,
// min-key tie-break on (dist,index)).
__global__ __launch_bounds__(256) void refine_kernel(
    const float* __restrict__ x, const float* __restrict__ w,
    const float* __restrict__ wn32,
    const int* __restrict__ flagList, const int* __restrict__ flagcnt,
    int* __restrict__ idx_i, int* __restrict__ counts_i)
{
  __shared__ double xd[RT][DDIM];                    // 32 KB
  __shared__ float  a32[RT];
  __shared__ unsigned long long wred[4][RT];
  int tid = threadIdx.x;
  int lane = tid & 63, wid = tid >> 6;
  int nf = *flagcnt;
  for (int b0 = blockIdx.x * RT; b0 < nf; b0 += gridDim.x * RT) {
    // ---- stage: wave wid loads token slots 2*wid, 2*wid+1 ----
    #pragma unroll
    for (int tt = 0; tt < 2; tt++) {
      int ts = wid * 2 + tt;
      int fi = b0 + ts;
      if (fi < nf) {
        int token = flagList[fi];
        double s = 0.0;
        #pragma unroll
        for (int it = 0; it < 2; it++) {
          int e4 = lane + it * 64;
          float4 v = *(const float4*)(x + (size_t)token * DDIM + e4 * 4);
          double vx = (double)v.x, vy = (double)v.y, vz = (double)v.z, vw = (double)v.w;
          xd[ts][e4 * 4 + 0] = vx;
          xd[ts][e4 * 4 + 1] = vy;
          xd[ts][e4 * 4 + 2] = vz;
          xd[ts][e4 * 4 + 3] = vw;
          s += vx * vx + vy * vy + vz * vz + vw * vw;
        }
        for (int o = 32; o > 0; o >>= 1) s += __shfl_down(s, o, 64);
        if (lane == 0) a32[ts] = (float)s;
      } else {
        #pragma unroll
        for (int it = 0; it < 2; it++) {
          int e4 = lane + it * 64;
          xd[ts][e4 * 4 + 0] = 0.0; xd[ts][e4 * 4 + 1] = 0.0;
          xd[ts][e4 * 4 + 2] = 0.0; xd[ts][e4 * 4 + 3] = 0.0;
        }
        if (lane == 0) a32[ts] = 0.f;
      }
    }
    __syncthreads();

    // ---- sweep codebook: thread handles codes c*256+tid ----
    unsigned long long key[RT];
    #pragma unroll
    for (int t = 0; t < RT; t++) key[t] = ~0ull;
    for (int c = 0; c < 4; c++) {
      int k = c * 256 + tid;
      if (k == 0) continue;                  // pad code excluded
      const float4* wr = (const float4*)(w + (size_t)k * DDIM);
      double dacc[RT];
      #pragma unroll
      for (int t = 0; t < RT; t++) dacc[t] = 0.0;
      for (int dq = 0; dq < DDIM / 4; dq++) {
        float4 wv = wr[dq];
        double wx = (double)wv.x, wy = (double)wv.y, wz = (double)wv.z, ww2 = (double)wv.w;
        #pragma unroll
        for (int t = 0; t < RT; t++) {
          dacc[t] += xd[t][dq*4+0]*wx + xd[t][dq*4+1]*wy
                   + xd[t][dq*4+2]*wz + xd[t][dq*4+3]*ww2;
        }
      }
      float wnk = wn32[k];
      #pragma unroll
      for (int t = 0; t < RT; t++) {
        float M = (float)dacc[t];
        float AB = a32[t] + wnk;
        float dist = AB - 2.0f * M;
        unsigned long long kk = ((unsigned long long)ordf(dist) << 32) | (unsigned)k;
        if (kk < key[t]) key[t] = kk;
      }
    }

    // ---- reduce 256 threads -> 1 per token ----
    #pragma unroll
    for (int t = 0; t < RT; t++) {
      unsigned long long kk = key[t];
      for (int o = 32; o > 0; o >>= 1) {
        unsigned long long ok = __shfl_down(kk, o, 64);
        if (ok < kk) kk = ok;
      }
      if (lane == 0) wred[wid][t] = kk;
    }
    __syncthreads();
    if (tid < RT) {
      int fi = b0 + tid;
      if (fi < nf) {
        unsigned long long kk = wred[0][tid];
        if (wred[1][tid] < kk) kk = wred[1][tid];
        if (wred[2][tid] < kk) kk = wred[2][tid];
        if (wred[3][tid] < kk) kk = wred[3][tid];
        int token = flagList[fi];
        int old = idx_i[token];
        int nw = (int)(kk & 0xffffffffu);
        if (nw != old) {
          idx_i[token] = nw;
          atomicSub(&counts_i[old], 1);
          atomicAdd(&counts_i[nw], 1);
        }
      }
    }
    __syncthreads();   // xd reused next batch
  }
}

// ---------------- exclusive scan of counts ----------------
__global__ __launch_bounds__(1024) void scan_kernel(
    const int* __restrict__ counts_i, int* __restrict__ offsets, int* __restrict__ cursor)
{
  __shared__ int tmp[1024];
  int t = threadIdx.x;
  int c = counts_i[t];
  tmp[t] = c;
  __syncthreads();
  for (int off = 1; off < 1024; off <<= 1) {
    int v = (t >= off) ? tmp[t - off] : 0;
    __syncthreads();
    tmp[t] += v;
    __syncthreads();
  }
  int ex = tmp[t] - c;
  offsets[t] = ex;
  cursor[t] = ex;
}

// ---------------- scatter with LDS rank aggregation ----------------
__global__ __launch_bounds__(1024) void scatter_kernel(
    const int* __restrict__ idx_i, int* __restrict__ cursor, int* __restrict__ bucket)
{
  __shared__ int lh[KCODE];
  __shared__ int lb[KCODE];
  int tid = threadIdx.x;
  lh[tid] = 0;
  __syncthreads();
  int token = blockIdx.x * 1024 + tid;
  int id = idx_i[token];
  int r = atomicAdd(&lh[id], 1);
  __syncthreads();
  if (lh[tid] > 0) lb[tid] = atomicAdd(&cursor[tid], lh[tid]);
  __syncthreads();
  bucket[lb[id] + r] = token;
}

// ---------------- quantized output + out_idx + loss ----------------
__global__ __launch_bounds__(256) void quant_kernel(
    const float* __restrict__ x, const float* __restrict__ w,
    const int* __restrict__ idx_i,
    float* __restrict__ out_q, float* __restrict__ out_idx, float* __restrict__ losssum)
{
  __shared__ float sred[4];
  int tid = threadIdx.x;
  int qd = tid & 127, h = tid >> 7;
  float s = 0.f;
  #pragma unroll
  for (int i = 0; i < 8; i++) {
    int token = blockIdx.x * 16 + i * 2 + h;
    int idx = idx_i[token];
    float4 xv = *(const float4*)(x + (size_t)token * DDIM + qd * 4);
    float4 wv = *(const float4*)(w + (size_t)idx * DDIM + qd * 4);
    *(float4*)(out_q + (size_t)token * DDIM + qd * 4) = wv;
    if (qd == 0) out_idx[token] = (float)idx;
    float dx = wv.x - xv.x, dy = wv.y - xv.y, dz = wv.z - xv.z, dww = wv.w - xv.w;
    s += dx*dx + dy*dy + dz*dz + dww*dww;
  }
  for (int o = 32; o > 0; o >>= 1) s += __shfl_down(s, o, 64);
  int lane = tid & 63, wid = tid >> 6;
  if (lane == 0) sred[wid] = s;
  __syncthreads();
  if (tid == 0) atomicAdd(losssum, sred[0] + sred[1] + sred[2] + sred[3]);
}

// ---------------- dw: balanced contiguous bucket ranges, run-flush atomics ----------------
__global__ __launch_bounds__(128) void dw_kernel(
    const float* __restrict__ x, const int* __restrict__ bucket,
    const int* __restrict__ idx_i, float* __restrict__ dw)
{
  int b0 = blockIdx.x * 32;
  int t = threadIdx.x;
  int ent = bucket[b0 + (t & 31)];
  int eid = idx_i[ent];
  int tok0 = __shfl(ent, 0, 64);
  int cur  = __shfl(eid, 0, 64);
  float4 acc = make_float4(0.f, 0.f, 0.f, 0.f);
  float4 nv = *(const float4*)(x + (size_t)tok0 * DDIM + t * 4);
  for (int j = 0; j < 32; j++) {
    float4 v = nv;
    int id = __shfl(eid, j, 64);
    if (j < 31) {
      int tn = __shfl(ent, j + 1, 64);
      nv = *(const float4*)(x + (size_t)tn * DDIM + t * 4);
    }
    if (id != cur) {   // wave-uniform branch
      float* p = dw + (size_t)cur * DDIM + t * 4;
      atomicAdd(p + 0, acc.x); atomicAdd(p + 1, acc.y);
      atomicAdd(p + 2, acc.z); atomicAdd(p + 3, acc.w);
      acc = make_float4(0.f, 0.f, 0.f, 0.f);
      cur = id;
    }
    acc.x += v.x; acc.y += v.y; acc.z += v.z; acc.w += v.w;
  }
  float* p = dw + (size_t)cur * DDIM + t * 4;
  atomicAdd(p + 0, acc.x); atomicAdd(p + 1, acc.y);
  atomicAdd(p + 2, acc.z); atomicAdd(p + 3, acc.w);
}

// ---------------- cs / loss / perplexity ----------------
__global__ __launch_bounds__(1024) void stats_kernel(
    const int* __restrict__ counts_i, const float* __restrict__ ema_cs,
    const float* __restrict__ losssum,
    float* __restrict__ out_loss, float* __restrict__ out_perp,
    float* __restrict__ out_cs)
{
  __shared__ float sbuf[17];
  int k = threadIdx.x;
  float cnt = (float)counts_i[k];
  float csr = ema_cs[k] * DECAYF + (1.f - DECAYF) * cnt;
  float v = csr;
  for (int o = 32; o > 0; o >>= 1) v += __shfl_down(v, o, 64);
  int lane = k & 63, wid = k >> 6;
  if (lane == 0) sbuf[wid] = v;
  __syncthreads();
  if (k == 0) { float n = 0.f; for (int i = 0; i < 16; i++) n += sbuf[i]; sbuf[16] = n; }
  __syncthreads();
  float n = sbuf[16];
  out_cs[k] = (csr + EPSV) / (n + (float)KCODE * EPSV) * n;
  __syncthreads();
  float p = cnt / (float)N_TOK;
  v = p * logf(p + 1e-10f);
  for (int o = 32; o > 0; o >>= 1) v += __shfl_down(v, o, 64);
  if (lane == 0) sbuf[wid] = v;
  __syncthreads();
  if (k == 0) {
    float s = 0.f; for (int i = 0; i < 16; i++) s += sbuf[i];
    out_perp[0] = expf(-s);
    float nonpad = (float)(N_TOK - counts_i[0]);
    out_loss[0] = CCOST * losssum[0] / (nonpad * (float)DDIM);
  }
}

// ---------------- EMA update + new codebook ----------------
__global__ __launch_bounds__(256) void ema_kernel(
    const float* __restrict__ ema_w, const float* __restrict__ dw,
    const float* __restrict__ cs,
    float* __restrict__ out_ema, float* __restrict__ out_cb)
{
  int i = blockIdx.x * 256 + threadIdx.x;
  int e = i * 4;
  int k = e >> 9;
  float4 dv = *(const float4*)(dw + e);
  float4 ew = *(const float4*)(ema_w + e);
  float4 ne;
  ne.x = ew.x * DECAYF + (1.f - DECAYF) * dv.x;
  ne.y = ew.y * DECAYF + (1.f - DECAYF) * dv.y;
  ne.z = ew.z * DECAYF + (1.f - DECAYF) * dv.z;
  ne.w = ew.w * DECAYF + (1.f - DECAYF) * dv.w;
  *(float4*)(out_ema + e) = ne;
  float4 cb;
  if (k == 0) { cb.x = 0.f; cb.y = 0.f; cb.z = 0.f; cb.w = 0.f; }
  else {
    float csk = cs[k];
    cb.x = ne.x / csk; cb.y = ne.y / csk; cb.z = ne.z / csk; cb.w = ne.w / csk;
  }
  *(float4*)(out_cb + e) = cb;
}

extern "C" void kernel_launch(void* const* d_in, const int* in_sizes, int n_in,
                              void* d_out, int out_size, void* d_ws, size_t ws_size,
                              hipStream_t stream) {
  const float* x      = (const float*)d_in[0];
  const int*   mask   = (const int*)d_in[1];
  const float* w      = (const float*)d_in[2];
  const float* ema_cs = (const float*)d_in[3];
  const float* ema_w  = (const float*)d_in[4];
  float* out = (float*)d_out;

  float* out_q    = out;                  // 16777216  quantized_st
  float* out_idx  = out + 16777216;       // 32768     idx (as float)
  float* out_loss = out + 16809984;       // 1
  float* out_perp = out + 16809985;       // 1
  float* out_cs   = out + 16809986;       // 1024
  float* out_ema  = out + 16811010;       // 524288
  float* out_cb   = out + 17335298;       // 524288

  // xhi lives in the (dead until quant) out_q region: 32 MB
  unsigned short* xhi = (unsigned short*)out_q;

  char* ws = (char*)d_ws;
  int*   counts_i = (int*)  (ws + 0);          // 4 KB   (zeroed)
  float* dw       = (float*)(ws + 4096);       // 2 MB   (zeroed)
  float* losssum  = (float*)(ws + 2101248);    // 4 B    (zeroed)
  int*   flagcnt  = (int*)  (ws + 2101252);    // 4 B    (zeroed)
  int*   offsets  = (int*)  (ws + 2101312);    // 4 KB
  int*   cursor   = (int*)  (ws + 2105408);    // 4 KB
  float* wn       = (float*)(ws + 2109504);    // 4 KB
  int*   idx_i    = (int*)  (ws + 2113600);    // 128 KB
  int*   bucket   = (int*)  (ws + 2244672);    // 128 KB
  unsigned short* whi = (unsigned short*)(ws + 2375744);   // 1 MB
  unsigned long long* k1buf = (unsigned long long*)(ws + 4472896);  // 4 MB
  unsigned long long* k2buf = (unsigned long long*)(ws + 8667200);  // 4 MB
  int*   flagList = (int*)  (ws + 12861504);   // 128 KB -> total ~13 MB

  hipMemsetAsync(ws, 0, 2101256, stream);  // counts + dw + losssum + flagcnt
  convert_fused<<<16384 + 256, 256, 0, stream>>>(x, w, xhi, whi, wn);
  dist_mfma<<<(N_TOK / 128) * 8, 256, 0, stream>>>(xhi, whi, wn, k1buf, k2buf);
  combine_kernel<<<N_TOK / 1024, 1024, 0, stream>>>(k1buf, k2buf, mask, idx_i, flagList, flagcnt, counts_i);
  refine_kernel<<<512, 256, 0, stream>>>(x, w, wn, flagList, flagcnt, idx_i, counts_i);
  scan_kernel<<<1, 1024, 0, stream>>>(counts_i, offsets, cursor);
  scatter_kernel<<<N_TOK / 1024, 1024, 0, stream>>>(idx_i, cursor, bucket);
  quant_kernel<<<N_TOK / 16, 256, 0, stream>>>(x, w, idx_i, out_q, out_idx, losssum);
  dw_kernel<<<N_TOK / 32, 128, 0, stream>>>(x, bucket, idx_i, dw);
  stats_kernel<<<1, 1024, 0, stream>>>(counts_i, ema_cs, losssum, out_loss, out_perp, out_cs);
  ema_kernel<<<KCODE * DDIM / 4 / 256, 256, 0, stream>>>(ema_w, dw, out_cs, out_ema, out_cb);
}

// Round 7
// 432.455 us; speedup vs baseline: 3.3041x; 1.1277x over previous
//
#include <hip/hip_runtime.h>
#include <math.h>

#define N_TOK 32768
#define DDIM  512
#define KCODE 1024
#define DECAYF 0.99f
#define EPSV 1e-5f
#define CCOST 0.25f
#define MARGIN 0.02f   // hi-only dist-diff err std ~3.2e-3 -> 6 sigma; flags ~13% of tokens
#define RT 8           // refine: tokens per work unit

typedef float f32x4 __attribute__((ext_vector_type(4)));
typedef short short8v __attribute__((ext_vector_type(8)));

// ---- bf16 helpers (RTN-even) ----
__device__ __forceinline__ unsigned short f2bf(float f) {
  unsigned u = __float_as_uint(f);
  u += 0x7fffu + ((u >> 16) & 1u);
  return (unsigned short)(u >> 16);
}
__device__ __forceinline__ float bf2f(unsigned short h) {
  return __uint_as_float(((unsigned)h) << 16);
}

// ---- monotone float<->ordered-uint for argmin key packing ----
__device__ __forceinline__ unsigned ordf(float f) {
  unsigned u = __float_as_uint(f);
  return (u & 0x80000000u) ? ~u : (u | 0x80000000u);
}
__device__ __forceinline__ float ord2f(unsigned v) {
  unsigned u = (v & 0x80000000u) ? (v & 0x7fffffffu) : ~v;
  return __uint_as_float(u);
}
__device__ __forceinline__ void top2m(unsigned long long& a1, unsigned long long& a2,
                                      unsigned long long b1, unsigned long long b2) {
  unsigned long long m1 = a1 < b1 ? a1 : b1;
  unsigned long long hi = a1 < b1 ? b1 : a1;
  unsigned long long m2 = a2 < b2 ? a2 : b2;
  a2 = m2 < hi ? m2 : hi;
  a1 = m1;
}

// ---- async global->LDS, 16B/lane ----
__device__ __forceinline__ void stage16(const void* g, char* lds_base, int lane) {
#if __has_builtin(__builtin_amdgcn_global_load_lds)
  __builtin_amdgcn_global_load_lds((const __attribute__((address_space(1))) void*)g,
                                   (__attribute__((address_space(3))) void*)lds_base,
                                   16, 0, 0);
#else
  *(float4*)(lds_base + lane * 16) = *(const float4*)g;
#endif
}

// ---------------- fused conversion: x and w -> bf16 hi, + w fp64 norms ----------------
__global__ __launch_bounds__(256) void convert_fused(
    const float* __restrict__ x, const float* __restrict__ w,
    unsigned short* __restrict__ xhi, unsigned short* __restrict__ whi,
    float* __restrict__ wn)
{
  int b = blockIdx.x;
  int tid = threadIdx.x;
  if (b < 16384) {              // x part: 16384 blocks x 256 thr x float4
    size_t i = (size_t)b * 256 + tid;
    float4 v = *(const float4*)(x + i * 4);
    ushort4 h;
    h.x = f2bf(v.x);
    h.y = f2bf(v.y);
    h.z = f2bf(v.z);
    h.w = f2bf(v.w);
    *(ushort4*)(xhi + i * 4) = h;
  } else {                      // w part: 256 blocks, each wave handles one row
    int k = (b - 16384) * 4 + (tid >> 6);
    int lane = tid & 63;
    double s = 0.0;
    #pragma unroll
    for (int it = 0; it < 2; it++) {
      size_t off = (size_t)k * DDIM + (lane + 64 * it) * 4;
      float4 v = *(const float4*)(w + off);
      s += (double)v.x*(double)v.x + (double)v.y*(double)v.y
         + (double)v.z*(double)v.z + (double)v.w*(double)v.w;
      ushort4 h;
      h.x = f2bf(v.x);
      h.y = f2bf(v.y);
      h.z = f2bf(v.z);
      h.w = f2bf(v.w);
      *(ushort4*)(whi + off) = h;
    }
    for (int o = 32; o > 0; o >>= 1) s += __shfl_down(s, o, 64);
    if (lane == 0) wn[k] = (float)s;
  }
}

// ---------------- MFMA distance + top-2 argmin (R8 structure, unchanged) ----------------
__global__ __launch_bounds__(256) void dist_mfma(
    const unsigned short* __restrict__ xhi, const unsigned short* __restrict__ whi,
    const float* __restrict__ wn,
    unsigned long long* __restrict__ k1buf, unsigned long long* __restrict__ k2buf)
{
  __shared__ __align__(16) short sA[128 * 32];
  __shared__ __align__(16) short sB[128 * 32];
  const int tid = threadIdx.x;
  const int wv = tid >> 6, lane = tid & 63;
  const int wg = (blockIdx.x & 7) * 256 + (blockIdx.x >> 3);
  const int tb = wg >> 3, kb = wg & 7;
  const int row0 = tb * 128, col0 = kb * 128;
  const int rw = wv & 1, cw = wv >> 1;
  const int q = lane >> 4, cl = lane & 15;
  const int swz = (cl >> 1) & 3;

  f32x4 acc[4][4];
  #pragma unroll
  for (int mt = 0; mt < 4; mt++)
    #pragma unroll
    for (int nt = 0; nt < 4; nt++) acc[mt][nt] = (f32x4){0.f, 0.f, 0.f, 0.f};

  const int cA0 = wv * 64 + lane;
  const int r0 = cA0 >> 2;
  const int s0 = (cA0 & 3) ^ ((r0 >> 1) & 3);
  const size_t aoff0 = (size_t)(row0 + r0) * 1024 + (size_t)s0 * 16;
  const size_t boff0 = (size_t)(col0 + r0) * 1024 + (size_t)s0 * 16;
  const char* pxh = (const char*)xhi;
  const char* pwh = (const char*)whi;

  const int aidx = (rw * 64 + cl) * 32 + (q ^ swz) * 8;
  const int bidx = (cw * 64 + cl) * 32 + (q ^ swz) * 8;

  for (int ks = 0; ks < 16; ks++) {
    const int k2 = ks * 64;
    __syncthreads();
    stage16(pxh + aoff0 + k2,         (char*)sA + wv * 1024, lane);
    stage16(pxh + aoff0 + 65536 + k2, (char*)sA + (wv + 4) * 1024, lane);
    stage16(pwh + boff0 + k2,         (char*)sB + wv * 1024, lane);
    stage16(pwh + boff0 + 65536 + k2, (char*)sB + (wv + 4) * 1024, lane);
    __syncthreads();

    short8v a[4], b[4];
    #pragma unroll
    for (int mt = 0; mt < 4; mt++) a[mt] = *(const short8v*)(sA + aidx + mt * 512);
    #pragma unroll
    for (int nt = 0; nt < 4; nt++) b[nt] = *(const short8v*)(sB + bidx + nt * 512);
    #pragma unroll
    for (int mt = 0; mt < 4; mt++)
      #pragma unroll
      for (int nt = 0; nt < 4; nt++)
        acc[mt][nt] = __builtin_amdgcn_mfma_f32_16x16x32_bf16(a[mt], b[nt], acc[mt][nt], 0, 0, 0);
  }

  float wnv[4];
  #pragma unroll
  for (int nt = 0; nt < 4; nt++) wnv[nt] = wn[col0 + cw * 64 + nt * 16 + cl];

  const int strip = kb * 2 + cw;
  #pragma unroll
  for (int mt = 0; mt < 4; mt++) {
    #pragma unroll
    for (int r = 0; r < 4; r++) {
      unsigned long long k1 = ~0ull, k2 = ~0ull;
      #pragma unroll
      for (int nt = 0; nt < 4; nt++) {
        int kk = col0 + cw * 64 + nt * 16 + cl;
        float dist = fmaf(-2.f, acc[mt][nt][r], wnv[nt]);
        unsigned long long key = (kk == 0) ? ~0ull
            : ((unsigned long long)ordf(dist) << 32) | (unsigned)kk;
        if (key < k1) { k2 = k1; k1 = key; }
        else if (key < k2) k2 = key;
      }
      #pragma unroll
      for (int off = 8; off > 0; off >>= 1) {
        unsigned long long o1 = __shfl_down(k1, off, 16);
        unsigned long long o2 = __shfl_down(k2, off, 16);
        top2m(k1, k2, o1, o2);
      }
      if (cl == 0) {
        int rowg = row0 + rw * 64 + mt * 16 + q * 4 + r;
        k1buf[strip * N_TOK + rowg] = k1;
        k2buf[strip * N_TOK + rowg] = k2;
      }
    }
  }
}

// ---------------- merge strips + pad mask + margin flag + LDS histogram ----------------
__global__ __launch_bounds__(1024) void combine_kernel(
    const unsigned long long* __restrict__ k1buf, const unsigned long long* __restrict__ k2buf,
    const int* __restrict__ mask,
    int* __restrict__ idx_i, int* __restrict__ flagList, int* __restrict__ flagcnt,
    int* __restrict__ counts_i)
{
  __shared__ int lh[KCODE];
  int tid = threadIdx.x;
  lh[tid] = 0;
  __syncthreads();
  int t = blockIdx.x * 1024 + tid;
  unsigned long long a1 = ~0ull, a2 = ~0ull;
  #pragma unroll
  for (int s = 0; s < 16; s++)
    top2m(a1, a2, k1buf[s * N_TOK + t], k2buf[s * N_TOK + t]);
  int bi = (int)(a1 & 0xffffffffu);
  float d1 = ord2f((unsigned)(a1 >> 32));
  float d2 = ord2f((unsigned)(a2 >> 32));
  int pad = mask[t];
  int id = pad ? 0 : bi;
  idx_i[t] = id;
  atomicAdd(&lh[id], 1);
  if (!pad && (d2 - d1) < MARGIN) {
    int p = atomicAdd(flagcnt, 1);
    flagList[p] = t;
  }
  __syncthreads();
  if (lh[tid] > 0) atomicAdd(&counts_i[tid], lh[tid]);
}

// ---------------- exact re-check, work-unit split: (8 tokens) x (256-code quarter) ----------------
// R10: R9's refine was 203us at 28% of the fp64 roofline: 2 blocks/CU gave
// 2 waves/SIMD (no latency hiding for the per-lane-row w loads) and the
// batch granularity left a 2x serial tail. Now each unit is a quarter of the
// codebook for 8 tokens: 4x more units -> 4 blocks/CU resident (4 waves/SIMD),
// ~1 light unit per block, w-load prefetched one dq ahead. Quarters merge via
// atomicMin on packed (ordf(dist),k) keys -> same ordering semantics as before.
__global__ __launch_bounds__(256) void refine_kernel(
    const float* __restrict__ x, const float* __restrict__ w,
    const float* __restrict__ wn32,
    const int* __restrict__ flagList, const int* __restrict__ flagcnt,
    unsigned long long* __restrict__ keyMin)
{
  __shared__ double xd[RT][DDIM];                    // 32 KB
  __shared__ float  a32[RT];
  __shared__ unsigned long long wred[4][RT];
  int tid = threadIdx.x;
  int lane = tid & 63, wid = tid >> 6;
  int nf = *flagcnt;
  int nu = ((nf + RT - 1) / RT) * 4;                 // units = token-batches x 4 quarters
  for (int u = blockIdx.x; u < nu; u += gridDim.x) {
    int fi0 = (u >> 2) * RT;
    int qq = u & 3;
    // ---- stage: wave wid loads token slots 2*wid, 2*wid+1 ----
    #pragma unroll
    for (int tt = 0; tt < 2; tt++) {
      int ts = wid * 2 + tt;
      int fi = fi0 + ts;
      if (fi < nf) {
        int token = flagList[fi];
        double s = 0.0;
        #pragma unroll
        for (int it = 0; it < 2; it++) {
          int e4 = lane + it * 64;
          float4 v = *(const float4*)(x + (size_t)token * DDIM + e4 * 4);
          double vx = (double)v.x, vy = (double)v.y, vz = (double)v.z, vw = (double)v.w;
          xd[ts][e4 * 4 + 0] = vx;
          xd[ts][e4 * 4 + 1] = vy;
          xd[ts][e4 * 4 + 2] = vz;
          xd[ts][e4 * 4 + 3] = vw;
          s += vx * vx + vy * vy + vz * vz + vw * vw;
        }
        for (int o = 32; o > 0; o >>= 1) s += __shfl_down(s, o, 64);
        if (lane == 0) a32[ts] = (float)s;
      } else {
        #pragma unroll
        for (int it = 0; it < 2; it++) {
          int e4 = lane + it * 64;
          xd[ts][e4 * 4 + 0] = 0.0; xd[ts][e4 * 4 + 1] = 0.0;
          xd[ts][e4 * 4 + 2] = 0.0; xd[ts][e4 * 4 + 3] = 0.0;
        }
        if (lane == 0) a32[ts] = 0.f;
      }
    }
    __syncthreads();

    // ---- this thread's single code within the quarter ----
    unsigned long long key[RT];
    #pragma unroll
    for (int t = 0; t < RT; t++) key[t] = ~0ull;
    int k = qq * 256 + tid;
    if (k != 0) {                            // pad code excluded
      const float4* wr = (const float4*)(w + (size_t)k * DDIM);
      double dacc[RT];
      #pragma unroll
      for (int t = 0; t < RT; t++) dacc[t] = 0.0;
      float4 wv = wr[0];                     // prefetch depth 1
      for (int dq = 0; dq < DDIM / 4; dq++) {
        float4 cv = wv;
        if (dq < DDIM / 4 - 1) wv = wr[dq + 1];
        double wx = (double)cv.x, wy = (double)cv.y, wz = (double)cv.z, ww2 = (double)cv.w;
        #pragma unroll
        for (int t = 0; t < RT; t++) {
          dacc[t] += xd[t][dq*4+0]*wx + xd[t][dq*4+1]*wy
                   + xd[t][dq*4+2]*wz + xd[t][dq*4+3]*ww2;
        }
      }
      float wnk = wn32[k];
      #pragma unroll
      for (int t = 0; t < RT; t++) {
        float M = (float)dacc[t];
        float AB = a32[t] + wnk;
        float dist = AB - 2.0f * M;
        key[t] = ((unsigned long long)ordf(dist) << 32) | (unsigned)k;
      }
    }

    // ---- reduce 256 threads -> 1 per token, then global atomicMin ----
    #pragma unroll
    for (int t = 0; t < RT; t++) {
      unsigned long long kk = key[t];
      for (int o = 32; o > 0; o >>= 1) {
        unsigned long long ok = __shfl_down(kk, o, 64);
        if (ok < kk) kk = ok;
      }
      if (lane == 0) wred[wid][t] = kk;
    }
    __syncthreads();
    if (tid < RT) {
      int fi = fi0 + tid;
      if (fi < nf) {
        unsigned long long kk = wred[0][tid];
        if (wred[1][tid] < kk) kk = wred[1][tid];
        if (wred[2][tid] < kk) kk = wred[2][tid];
        if (wred[3][tid] < kk) kk = wred[3][tid];
        if (kk != ~0ull) atomicMin(&keyMin[fi], kk);
      }
    }
    __syncthreads();   // xd/wred reused next unit
  }
}

// ---------------- apply keyMin -> idx/counts, restore dw zeros ----------------
__global__ __launch_bounds__(256) void finalize_kernel(
    const int* __restrict__ flagList, const int* __restrict__ flagcnt,
    unsigned long long* __restrict__ keyMin,
    int* __restrict__ idx_i, int* __restrict__ counts_i)
{
  int fi = blockIdx.x * 256 + threadIdx.x;   // grid 128 -> all 32768 slots
  int nf = *flagcnt;
  if (fi < nf) {
    unsigned long long kk = keyMin[fi];
    int token = flagList[fi];
    int nw = (int)(kk & 0xffffffffu);
    int old = idx_i[token];
    if (nw != old) {
      idx_i[token] = nw;
      atomicSub(&counts_i[old], 1);
      atomicAdd(&counts_i[nw], 1);
    }
  }
  keyMin[fi] = 0ull;   // keyMin aliases the head of dw: restore zeros for dw_kernel
}

// ---------------- exclusive scan of counts ----------------
__global__ __launch_bounds__(1024) void scan_kernel(
    const int* __restrict__ counts_i, int* __restrict__ offsets, int* __restrict__ cursor)
{
  __shared__ int tmp[1024];
  int t = threadIdx.x;
  int c = counts_i[t];
  tmp[t] = c;
  __syncthreads();
  for (int off = 1; off < 1024; off <<= 1) {
    int v = (t >= off) ? tmp[t - off] : 0;
    __syncthreads();
    tmp[t] += v;
    __syncthreads();
  }
  int ex = tmp[t] - c;
  offsets[t] = ex;
  cursor[t] = ex;
}

// ---------------- scatter with LDS rank aggregation ----------------
__global__ __launch_bounds__(1024) void scatter_kernel(
    const int* __restrict__ idx_i, int* __restrict__ cursor, int* __restrict__ bucket)
{
  __shared__ int lh[KCODE];
  __shared__ int lb[KCODE];
  int tid = threadIdx.x;
  lh[tid] = 0;
  __syncthreads();
  int token = blockIdx.x * 1024 + tid;
  int id = idx_i[token];
  int r = atomicAdd(&lh[id], 1);
  __syncthreads();
  if (lh[tid] > 0) lb[tid] = atomicAdd(&cursor[tid], lh[tid]);
  __syncthreads();
  bucket[lb[id] + r] = token;
}

// ---------------- quantized output + out_idx + loss ----------------
__global__ __launch_bounds__(256) void quant_kernel(
    const float* __restrict__ x, const float* __restrict__ w,
    const int* __restrict__ idx_i,
    float* __restrict__ out_q, float* __restrict__ out_idx, float* __restrict__ losssum)
{
  __shared__ float sred[4];
  int tid = threadIdx.x;
  int qd = tid & 127, h = tid >> 7;
  float s = 0.f;
  #pragma unroll
  for (int i = 0; i < 8; i++) {
    int token = blockIdx.x * 16 + i * 2 + h;
    int idx = idx_i[token];
    float4 xv = *(const float4*)(x + (size_t)token * DDIM + qd * 4);
    float4 wv = *(const float4*)(w + (size_t)idx * DDIM + qd * 4);
    *(float4*)(out_q + (size_t)token * DDIM + qd * 4) = wv;
    if (qd == 0) out_idx[token] = (float)idx;
    float dx = wv.x - xv.x, dy = wv.y - xv.y, dz = wv.z - xv.z, dww = wv.w - xv.w;
    s += dx*dx + dy*dy + dz*dz + dww*dww;
  }
  for (int o = 32; o > 0; o >>= 1) s += __shfl_down(s, o, 64);
  int lane = tid & 63, wid = tid >> 6;
  if (lane == 0) sred[wid] = s;
  __syncthreads();
  if (tid == 0) atomicAdd(losssum, sred[0] + sred[1] + sred[2] + sred[3]);
}

// ---------------- dw: balanced contiguous bucket ranges, run-flush atomics ----------------
__global__ __launch_bounds__(128) void dw_kernel(
    const float* __restrict__ x, const int* __restrict__ bucket,
    const int* __restrict__ idx_i, float* __restrict__ dw)
{
  int b0 = blockIdx.x * 32;
  int t = threadIdx.x;
  int ent = bucket[b0 + (t & 31)];
  int eid = idx_i[ent];
  int tok0 = __shfl(ent, 0, 64);
  int cur  = __shfl(eid, 0, 64);
  float4 acc = make_float4(0.f, 0.f, 0.f, 0.f);
  float4 nv = *(const float4*)(x + (size_t)tok0 * DDIM + t * 4);
  for (int j = 0; j < 32; j++) {
    float4 v = nv;
    int id = __shfl(eid, j, 64);
    if (j < 31) {
      int tn = __shfl(ent, j + 1, 64);
      nv = *(const float4*)(x + (size_t)tn * DDIM + t * 4);
    }
    if (id != cur) {   // wave-uniform branch
      float* p = dw + (size_t)cur * DDIM + t * 4;
      atomicAdd(p + 0, acc.x); atomicAdd(p + 1, acc.y);
      atomicAdd(p + 2, acc.z); atomicAdd(p + 3, acc.w);
      acc = make_float4(0.f, 0.f, 0.f, 0.f);
      cur = id;
    }
    acc.x += v.x; acc.y += v.y; acc.z += v.z; acc.w += v.w;
  }
  float* p = dw + (size_t)cur * DDIM + t * 4;
  atomicAdd(p + 0, acc.x); atomicAdd(p + 1, acc.y);
  atomicAdd(p + 2, acc.z); atomicAdd(p + 3, acc.w);
}

// ---------------- cs / loss / perplexity ----------------
__global__ __launch_bounds__(1024) void stats_kernel(
    const int* __restrict__ counts_i, const float* __restrict__ ema_cs,
    const float* __restrict__ losssum,
    float* __restrict__ out_loss, float* __restrict__ out_perp,
    float* __restrict__ out_cs)
{
  __shared__ float sbuf[17];
  int k = threadIdx.x;
  float cnt = (float)counts_i[k];
  float csr = ema_cs[k] * DECAYF + (1.f - DECAYF) * cnt;
  float v = csr;
  for (int o = 32; o > 0; o >>= 1) v += __shfl_down(v, o, 64);
  int lane = k & 63, wid = k >> 6;
  if (lane == 0) sbuf[wid] = v;
  __syncthreads();
  if (k == 0) { float n = 0.f; for (int i = 0; i < 16; i++) n += sbuf[i]; sbuf[16] = n; }
  __syncthreads();
  float n = sbuf[16];
  out_cs[k] = (csr + EPSV) / (n + (float)KCODE * EPSV) * n;
  __syncthreads();
  float p = cnt / (float)N_TOK;
  v = p * logf(p + 1e-10f);
  for (int o = 32; o > 0; o >>= 1) v += __shfl_down(v, o, 64);
  if (lane == 0) sbuf[wid] = v;
  __syncthreads();
  if (k == 0) {
    float s = 0.f; for (int i = 0; i < 16; i++) s += sbuf[i];
    out_perp[0] = expf(-s);
    float nonpad = (float)(N_TOK - counts_i[0]);
    out_loss[0] = CCOST * losssum[0] / (nonpad * (float)DDIM);
  }
}

// ---------------- EMA update + new codebook ----------------
__global__ __launch_bounds__(256) void ema_kernel(
    const float* __restrict__ ema_w, const float* __restrict__ dw,
    const float* __restrict__ cs,
    float* __restrict__ out_ema, float* __restrict__ out_cb)
{
  int i = blockIdx.x * 256 + threadIdx.x;
  int e = i * 4;
  int k = e >> 9;
  float4 dv = *(const float4*)(dw + e);
  float4 ew = *(const float4*)(ema_w + e);
  float4 ne;
  ne.x = ew.x * DECAYF + (1.f - DECAYF) * dv.x;
  ne.y = ew.y * DECAYF + (1.f - DECAYF) * dv.y;
  ne.z = ew.z * DECAYF + (1.f - DECAYF) * dv.z;
  ne.w = ew.w * DECAYF + (1.f - DECAYF) * dv.w;
  *(float4*)(out_ema + e) = ne;
  float4 cb;
  if (k == 0) { cb.x = 0.f; cb.y = 0.f; cb.z = 0.f; cb.w = 0.f; }
  else {
    float csk = cs[k];
    cb.x = ne.x / csk; cb.y = ne.y / csk; cb.z = ne.z / csk; cb.w = ne.w / csk;
  }
  *(float4*)(out_cb + e) = cb;
}

extern "C" void kernel_launch(void* const* d_in, const int* in_sizes, int n_in,
                              void* d_out, int out_size, void* d_ws, size_t ws_size,
                              hipStream_t stream) {
  const float* x      = (const float*)d_in[0];
  const int*   mask   = (const int*)d_in[1];
  const float* w      = (const float*)d_in[2];
  const float* ema_cs = (const float*)d_in[3];
  const float* ema_w  = (const float*)d_in[4];
  float* out = (float*)d_out;

  float* out_q    = out;                  // 16777216  quantized_st
  float* out_idx  = out + 16777216;       // 32768     idx (as float)
  float* out_loss = out + 16809984;       // 1
  float* out_perp = out + 16809985;       // 1
  float* out_cs   = out + 16809986;       // 1024
  float* out_ema  = out + 16811010;       // 524288
  float* out_cb   = out + 17335298;       // 524288

  // xhi lives in the (dead until quant) out_q region: 32 MB
  unsigned short* xhi = (unsigned short*)out_q;

  char* ws = (char*)d_ws;
  int*   counts_i = (int*)  (ws + 0);          // 4 KB   (zeroed)
  float* dw       = (float*)(ws + 4096);       // 2 MB   (zeroed)
  // keyMin aliases the first 256 KB of dw: memset 0xFF before use, finalize
  // restores zeros before dw_kernel consumes dw.
  unsigned long long* keyMin = (unsigned long long*)(ws + 4096);
  float* losssum  = (float*)(ws + 2101248);    // 4 B    (zeroed)
  int*   flagcnt  = (int*)  (ws + 2101252);    // 4 B    (zeroed)
  int*   offsets  = (int*)  (ws + 2101312);    // 4 KB
  int*   cursor   = (int*)  (ws + 2105408);    // 4 KB
  float* wn       = (float*)(ws + 2109504);    // 4 KB
  int*   idx_i    = (int*)  (ws + 2113600);    // 128 KB
  int*   bucket   = (int*)  (ws + 2244672);    // 128 KB
  unsigned short* whi = (unsigned short*)(ws + 2375744);   // 1 MB
  unsigned long long* k1buf = (unsigned long long*)(ws + 4472896);  // 4 MB
  unsigned long long* k2buf = (unsigned long long*)(ws + 8667200);  // 4 MB
  int*   flagList = (int*)  (ws + 12861504);   // 128 KB -> total ~13 MB

  hipMemsetAsync(ws, 0, 2101256, stream);        // counts + dw + losssum + flagcnt
  hipMemsetAsync(ws + 4096, 0xFF, 262144, stream); // keyMin = ~0ull (head of dw)
  convert_fused<<<16384 + 256, 256, 0, stream>>>(x, w, xhi, whi, wn);
  dist_mfma<<<(N_TOK / 128) * 8, 256, 0, stream>>>(xhi, whi, wn, k1buf, k2buf);
  combine_kernel<<<N_TOK / 1024, 1024, 0, stream>>>(k1buf, k2buf, mask, idx_i, flagList, flagcnt, counts_i);
  refine_kernel<<<2048, 256, 0, stream>>>(x, w, wn, flagList, flagcnt, keyMin);
  finalize_kernel<<<N_TOK / 256 / 1, 256, 0, stream>>>(flagList, flagcnt, keyMin, idx_i, counts_i);
  scan_kernel<<<1, 1024, 0, stream>>>(counts_i, offsets, cursor);
  scatter_kernel<<<N_TOK / 1024, 1024, 0, stream>>>(idx_i, cursor, bucket);
  quant_kernel<<<N_TOK / 16, 256, 0, stream>>>(x, w, idx_i, out_q, out_idx, losssum);
  dw_kernel<<<N_TOK / 32, 128, 0, stream>>>(x, bucket, idx_i, dw);
  stats_kernel<<<1, 1024, 0, stream>>>(counts_i, ema_cs, losssum, out_loss, out_perp, out_cs);
  ema_kernel<<<KCODE * DDIM / 4 / 256, 256, 0, stream>>>(ema_w, dw, out_cs, out_ema, out_cb);
}

// Round 8
// 378.689 us; speedup vs baseline: 3.7732x; 1.1420x over previous
//
#include <hip/hip_runtime.h>
#include <math.h>

#define N_TOK 32768
#define DDIM  512
#define KCODE 1024
#define DECAYF 0.99f
#define EPSV 1e-5f
#define CCOST 0.25f
#define MARGIN 0.02f    // coarse 1-pass hi*hi margin (validated R6/R7)
#define MARGIN2 1e-3f   // 3-pass exact-ish margin (validated R0-R3 contract)
#define RT 8            // micro-refine: tokens per work unit

typedef float f32x4 __attribute__((ext_vector_type(4)));
typedef short short8v __attribute__((ext_vector_type(8)));

// ---- bf16 helpers (RTN-even) ----
__device__ __forceinline__ unsigned short f2bf(float f) {
  unsigned u = __float_as_uint(f);
  u += 0x7fffu + ((u >> 16) & 1u);
  return (unsigned short)(u >> 16);
}
__device__ __forceinline__ float bf2f(unsigned short h) {
  return __uint_as_float(((unsigned)h) << 16);
}

// ---- monotone float<->ordered-uint for argmin key packing ----
__device__ __forceinline__ unsigned ordf(float f) {
  unsigned u = __float_as_uint(f);
  return (u & 0x80000000u) ? ~u : (u | 0x80000000u);
}
__device__ __forceinline__ float ord2f(unsigned v) {
  unsigned u = (v & 0x80000000u) ? (v & 0x7fffffffu) : ~v;
  return __uint_as_float(u);
}
__device__ __forceinline__ void top2m(unsigned long long& a1, unsigned long long& a2,
                                      unsigned long long b1, unsigned long long b2) {
  unsigned long long m1 = a1 < b1 ? a1 : b1;
  unsigned long long hi = a1 < b1 ? b1 : a1;
  unsigned long long m2 = a2 < b2 ? a2 : b2;
  a2 = m2 < hi ? m2 : hi;
  a1 = m1;
}

// ---- async global->LDS, 16B/lane ----
__device__ __forceinline__ void stage16(const void* g, char* lds_base, int lane) {
#if __has_builtin(__builtin_amdgcn_global_load_lds)
  __builtin_amdgcn_global_load_lds((const __attribute__((address_space(1))) void*)g,
                                   (__attribute__((address_space(3))) void*)lds_base,
                                   16, 0, 0);
#else
  *(float4*)(lds_base + lane * 16) = *(const float4*)g;
#endif
}

// ---------------- fused conversion: x and w -> bf16 hi/lo, + w fp64 norms ----------------
// R11: hi/lo restored (R0 code) — lo terms feed refine_mfma's 3-pass on flagged tokens.
__global__ __launch_bounds__(256) void convert_fused(
    const float* __restrict__ x, const float* __restrict__ w,
    unsigned short* __restrict__ xhi, unsigned short* __restrict__ xlo,
    unsigned short* __restrict__ whi, unsigned short* __restrict__ wlo,
    float* __restrict__ wn)
{
  int b = blockIdx.x;
  int tid = threadIdx.x;
  if (b < 16384) {              // x part: 16384 blocks x 256 thr x float4
    size_t i = (size_t)b * 256 + tid;
    float4 v = *(const float4*)(x + i * 4);
    ushort4 h, l;
    h.x = f2bf(v.x); l.x = f2bf(v.x - bf2f(h.x));
    h.y = f2bf(v.y); l.y = f2bf(v.y - bf2f(h.y));
    h.z = f2bf(v.z); l.z = f2bf(v.z - bf2f(h.z));
    h.w = f2bf(v.w); l.w = f2bf(v.w - bf2f(h.w));
    *(ushort4*)(xhi + i * 4) = h;
    *(ushort4*)(xlo + i * 4) = l;
  } else {                      // w part: 256 blocks, each wave handles one row
    int k = (b - 16384) * 4 + (tid >> 6);
    int lane = tid & 63;
    double s = 0.0;
    #pragma unroll
    for (int it = 0; it < 2; it++) {
      size_t off = (size_t)k * DDIM + (lane + 64 * it) * 4;
      float4 v = *(const float4*)(w + off);
      s += (double)v.x*(double)v.x + (double)v.y*(double)v.y
         + (double)v.z*(double)v.z + (double)v.w*(double)v.w;
      ushort4 h, l;
      h.x = f2bf(v.x); l.x = f2bf(v.x - bf2f(h.x));
      h.y = f2bf(v.y); l.y = f2bf(v.y - bf2f(h.y));
      h.z = f2bf(v.z); l.z = f2bf(v.z - bf2f(h.z));
      h.w = f2bf(v.w); l.w = f2bf(v.w - bf2f(h.w));
      *(ushort4*)(whi + off) = h;
      *(ushort4*)(wlo + off) = l;
    }
    for (int o = 32; o > 0; o >>= 1) s += __shfl_down(s, o, 64);
    if (lane == 0) wn[k] = (float)s;
  }
}

// ---------------- coarse MFMA distance (1-pass hi*hi) + top-2 argmin ----------------
__global__ __launch_bounds__(256) void dist_mfma(
    const unsigned short* __restrict__ xhi, const unsigned short* __restrict__ whi,
    const float* __restrict__ wn,
    unsigned long long* __restrict__ k1buf, unsigned long long* __restrict__ k2buf)
{
  __shared__ __align__(16) short sA[128 * 32];
  __shared__ __align__(16) short sB[128 * 32];
  const int tid = threadIdx.x;
  const int wv = tid >> 6, lane = tid & 63;
  const int wg = (blockIdx.x & 7) * 256 + (blockIdx.x >> 3);
  const int tb = wg >> 3, kb = wg & 7;
  const int row0 = tb * 128, col0 = kb * 128;
  const int rw = wv & 1, cw = wv >> 1;
  const int q = lane >> 4, cl = lane & 15;
  const int swz = (cl >> 1) & 3;

  f32x4 acc[4][4];
  #pragma unroll
  for (int mt = 0; mt < 4; mt++)
    #pragma unroll
    for (int nt = 0; nt < 4; nt++) acc[mt][nt] = (f32x4){0.f, 0.f, 0.f, 0.f};

  const int cA0 = wv * 64 + lane;
  const int r0 = cA0 >> 2;
  const int s0 = (cA0 & 3) ^ ((r0 >> 1) & 3);
  const size_t aoff0 = (size_t)(row0 + r0) * 1024 + (size_t)s0 * 16;
  const size_t boff0 = (size_t)(col0 + r0) * 1024 + (size_t)s0 * 16;
  const char* pxh = (const char*)xhi;
  const char* pwh = (const char*)whi;

  const int aidx = (rw * 64 + cl) * 32 + (q ^ swz) * 8;
  const int bidx = (cw * 64 + cl) * 32 + (q ^ swz) * 8;

  for (int ks = 0; ks < 16; ks++) {
    const int k2 = ks * 64;
    __syncthreads();
    stage16(pxh + aoff0 + k2,         (char*)sA + wv * 1024, lane);
    stage16(pxh + aoff0 + 65536 + k2, (char*)sA + (wv + 4) * 1024, lane);
    stage16(pwh + boff0 + k2,         (char*)sB + wv * 1024, lane);
    stage16(pwh + boff0 + 65536 + k2, (char*)sB + (wv + 4) * 1024, lane);
    __syncthreads();

    short8v a[4], b[4];
    #pragma unroll
    for (int mt = 0; mt < 4; mt++) a[mt] = *(const short8v*)(sA + aidx + mt * 512);
    #pragma unroll
    for (int nt = 0; nt < 4; nt++) b[nt] = *(const short8v*)(sB + bidx + nt * 512);
    #pragma unroll
    for (int mt = 0; mt < 4; mt++)
      #pragma unroll
      for (int nt = 0; nt < 4; nt++)
        acc[mt][nt] = __builtin_amdgcn_mfma_f32_16x16x32_bf16(a[mt], b[nt], acc[mt][nt], 0, 0, 0);
  }

  float wnv[4];
  #pragma unroll
  for (int nt = 0; nt < 4; nt++) wnv[nt] = wn[col0 + cw * 64 + nt * 16 + cl];

  const int strip = kb * 2 + cw;
  #pragma unroll
  for (int mt = 0; mt < 4; mt++) {
    #pragma unroll
    for (int r = 0; r < 4; r++) {
      unsigned long long k1 = ~0ull, k2 = ~0ull;
      #pragma unroll
      for (int nt = 0; nt < 4; nt++) {
        int kk = col0 + cw * 64 + nt * 16 + cl;
        float dist = fmaf(-2.f, acc[mt][nt][r], wnv[nt]);
        unsigned long long key = (kk == 0) ? ~0ull
            : ((unsigned long long)ordf(dist) << 32) | (unsigned)kk;
        if (key < k1) { k2 = k1; k1 = key; }
        else if (key < k2) k2 = key;
      }
      #pragma unroll
      for (int off = 8; off > 0; off >>= 1) {
        unsigned long long o1 = __shfl_down(k1, off, 16);
        unsigned long long o2 = __shfl_down(k2, off, 16);
        top2m(k1, k2, o1, o2);
      }
      if (cl == 0) {
        int rowg = row0 + rw * 64 + mt * 16 + q * 4 + r;
        k1buf[strip * N_TOK + rowg] = k1;
        k2buf[strip * N_TOK + rowg] = k2;
      }
    }
  }
}

// ---------------- merge strips + pad mask + margin flag + LDS histogram ----------------
__global__ __launch_bounds__(1024) void combine_kernel(
    const unsigned long long* __restrict__ k1buf, const unsigned long long* __restrict__ k2buf,
    const int* __restrict__ mask,
    int* __restrict__ idx_i, int* __restrict__ flagList, int* __restrict__ flagcnt,
    int* __restrict__ counts_i)
{
  __shared__ int lh[KCODE];
  int tid = threadIdx.x;
  lh[tid] = 0;
  __syncthreads();
  int t = blockIdx.x * 1024 + tid;
  unsigned long long a1 = ~0ull, a2 = ~0ull;
  #pragma unroll
  for (int s = 0; s < 16; s++)
    top2m(a1, a2, k1buf[s * N_TOK + t], k2buf[s * N_TOK + t]);
  int bi = (int)(a1 & 0xffffffffu);
  float d1 = ord2f((unsigned)(a1 >> 32));
  float d2 = ord2f((unsigned)(a2 >> 32));
  int pad = mask[t];
  int id = pad ? 0 : bi;
  idx_i[t] = id;
  atomicAdd(&lh[id], 1);
  if (!pad && (d2 - d1) < MARGIN) {
    int p = atomicAdd(flagcnt, 1);
    flagList[p] = t;
  }
  __syncthreads();
  if (lh[tid] > 0) atomicAdd(&counts_i[tid], lh[tid]);
}

// ---------------- 3-pass MFMA exact-ish dist on FLAGGED tokens (gathered A) ----------------
// R11: R1's validated merged-staging 3-seg kernel (hi*hi + hi*wlo + xlo*hi)
// applied to the flagged token list. A-rows gathered per-lane via flagList
// (global_load_lds source is per-lane). Strips written fi-indexed into
// k1buf/k2buf (dead after combine_kernel). ~272 busy blocks at nf~4300.
__global__ __launch_bounds__(256) void refine_mfma(
    const unsigned short* __restrict__ xhi, const unsigned short* __restrict__ xlo,
    const unsigned short* __restrict__ whi, const unsigned short* __restrict__ wlo,
    const float* __restrict__ wn,
    const int* __restrict__ flagList, const int* __restrict__ flagcnt,
    unsigned long long* __restrict__ k1buf, unsigned long long* __restrict__ k2buf)
{
  __shared__ __align__(16) short sAh[128 * 32];
  __shared__ __align__(16) short sAl[128 * 32];
  __shared__ __align__(16) short sBh[128 * 32];
  __shared__ __align__(16) short sBl[128 * 32];
  const int nf = *flagcnt;
  const int tb = blockIdx.x >> 3, kb = blockIdx.x & 7;
  const int fi0 = tb * 128;
  if (fi0 >= nf) return;
  const int tid = threadIdx.x;
  const int wv = tid >> 6, lane = tid & 63;
  const int col0 = kb * 128;
  const int rw = wv & 1, cw = wv >> 1;
  const int q = lane >> 4, cl = lane & 15;
  const int swz = (cl >> 1) & 3;

  f32x4 acc[4][4];
  #pragma unroll
  for (int mt = 0; mt < 4; mt++)
    #pragma unroll
    for (int nt = 0; nt < 4; nt++) acc[mt][nt] = (f32x4){0.f, 0.f, 0.f, 0.f};

  const int cA0 = wv * 64 + lane;
  const int r0 = cA0 >> 2;
  const int s0 = (cA0 & 3) ^ ((r0 >> 1) & 3);
  int fiA0 = fi0 + r0;      if (fiA0 > nf - 1) fiA0 = nf - 1;
  int fiA1 = fi0 + r0 + 64; if (fiA1 > nf - 1) fiA1 = nf - 1;
  const int tokA0 = flagList[fiA0];
  const int tokA1 = flagList[fiA1];
  const size_t aoff0 = (size_t)tokA0 * 1024 + (size_t)s0 * 16;
  const size_t aoff1 = (size_t)tokA1 * 1024 + (size_t)s0 * 16;
  const size_t boff0 = (size_t)(col0 + r0) * 1024 + (size_t)s0 * 16;
  const char* pxh = (const char*)xhi;
  const char* pxl = (const char*)xlo;
  const char* pwh = (const char*)whi;
  const char* pwl = (const char*)wlo;

  const int aidx = (rw * 64 + cl) * 32 + (q ^ swz) * 8;
  const int bidx = (cw * 64 + cl) * 32 + (q ^ swz) * 8;

  for (int ks = 0; ks < 16; ks++) {
    const int k2o = ks * 64;
    __syncthreads();
    stage16(pxh + aoff0 + k2o,         (char*)sAh + wv * 1024, lane);
    stage16(pxh + aoff1 + k2o,         (char*)sAh + (wv + 4) * 1024, lane);
    stage16(pxl + aoff0 + k2o,         (char*)sAl + wv * 1024, lane);
    stage16(pxl + aoff1 + k2o,         (char*)sAl + (wv + 4) * 1024, lane);
    stage16(pwh + boff0 + k2o,         (char*)sBh + wv * 1024, lane);
    stage16(pwh + boff0 + 65536 + k2o, (char*)sBh + (wv + 4) * 1024, lane);
    stage16(pwl + boff0 + k2o,         (char*)sBl + wv * 1024, lane);
    stage16(pwl + boff0 + 65536 + k2o, (char*)sBl + (wv + 4) * 1024, lane);
    __syncthreads();

    short8v ah[4], bh[4];
    #pragma unroll
    for (int mt = 0; mt < 4; mt++) ah[mt] = *(const short8v*)(sAh + aidx + mt * 512);
    #pragma unroll
    for (int nt = 0; nt < 4; nt++) bh[nt] = *(const short8v*)(sBh + bidx + nt * 512);
    #pragma unroll
    for (int mt = 0; mt < 4; mt++)
      #pragma unroll
      for (int nt = 0; nt < 4; nt++)
        acc[mt][nt] = __builtin_amdgcn_mfma_f32_16x16x32_bf16(ah[mt], bh[nt], acc[mt][nt], 0, 0, 0);

    short8v bl[4];
    #pragma unroll
    for (int nt = 0; nt < 4; nt++) bl[nt] = *(const short8v*)(sBl + bidx + nt * 512);
    #pragma unroll
    for (int mt = 0; mt < 4; mt++)
      #pragma unroll
      for (int nt = 0; nt < 4; nt++)
        acc[mt][nt] = __builtin_amdgcn_mfma_f32_16x16x32_bf16(ah[mt], bl[nt], acc[mt][nt], 0, 0, 0);

    short8v al[4];
    #pragma unroll
    for (int mt = 0; mt < 4; mt++) al[mt] = *(const short8v*)(sAl + aidx + mt * 512);
    #pragma unroll
    for (int mt = 0; mt < 4; mt++)
      #pragma unroll
      for (int nt = 0; nt < 4; nt++)
        acc[mt][nt] = __builtin_amdgcn_mfma_f32_16x16x32_bf16(al[mt], bh[nt], acc[mt][nt], 0, 0, 0);
  }

  float wnv[4];
  #pragma unroll
  for (int nt = 0; nt < 4; nt++) wnv[nt] = wn[col0 + cw * 64 + nt * 16 + cl];

  const int strip = kb * 2 + cw;
  #pragma unroll
  for (int mt = 0; mt < 4; mt++) {
    #pragma unroll
    for (int r = 0; r < 4; r++) {
      unsigned long long k1 = ~0ull, k2 = ~0ull;
      #pragma unroll
      for (int nt = 0; nt < 4; nt++) {
        int kk = col0 + cw * 64 + nt * 16 + cl;
        float dist = fmaf(-2.f, acc[mt][nt][r], wnv[nt]);
        unsigned long long key = (kk == 0) ? ~0ull
            : ((unsigned long long)ordf(dist) << 32) | (unsigned)kk;
        if (key < k1) { k2 = k1; k1 = key; }
        else if (key < k2) k2 = key;
      }
      #pragma unroll
      for (int off = 8; off > 0; off >>= 1) {
        unsigned long long o1 = __shfl_down(k1, off, 16);
        unsigned long long o2 = __shfl_down(k2, off, 16);
        top2m(k1, k2, o1, o2);
      }
      if (cl == 0) {
        int fig = fi0 + rw * 64 + mt * 16 + q * 4 + r;
        k1buf[strip * N_TOK + fig] = k1;
        k2buf[strip * N_TOK + fig] = k2;
      }
    }
  }
}

// ---------------- merge refine strips: patch idx/counts, flag residual ties ----------------
__global__ __launch_bounds__(256) void combine2_kernel(
    const unsigned long long* __restrict__ k1buf, const unsigned long long* __restrict__ k2buf,
    const int* __restrict__ flagList, const int* __restrict__ flagcnt,
    int* __restrict__ idx_i, int* __restrict__ counts_i,
    int* __restrict__ flagList2, int* __restrict__ flagcnt2)
{
  int fi = blockIdx.x * 256 + threadIdx.x;
  int nf = *flagcnt;
  if (fi >= nf) return;
  unsigned long long a1 = ~0ull, a2 = ~0ull;
  #pragma unroll
  for (int s = 0; s < 16; s++)
    top2m(a1, a2, k1buf[s * N_TOK + fi], k2buf[s * N_TOK + fi]);
  int token = flagList[fi];
  int nw = (int)(a1 & 0xffffffffu);
  float d1 = ord2f((unsigned)(a1 >> 32));
  float d2 = ord2f((unsigned)(a2 >> 32));
  int old = idx_i[token];
  if (nw != old) {
    idx_i[token] = nw;
    atomicSub(&counts_i[old], 1);
    atomicAdd(&counts_i[nw], 1);
  }
  if ((d2 - d1) < MARGIN2) {
    int p = atomicAdd(flagcnt2, 1);
    flagList2[p] = token;
  }
}

// ---------------- fp64 micro re-check (R10 structure, now ~tens of tokens) ----------------
__global__ __launch_bounds__(256) void refine_kernel(
    const float* __restrict__ x, const float* __restrict__ w,
    const float* __restrict__ wn32,
    const int* __restrict__ flagList, const int* __restrict__ flagcnt,
    unsigned long long* __restrict__ keyMin)
{
  __shared__ double xd[RT][DDIM];                    // 32 KB
  __shared__ float  a32[RT];
  __shared__ unsigned long long wred[4][RT];
  int tid = threadIdx.x;
  int lane = tid & 63, wid = tid >> 6;
  int nf = *flagcnt;
  int nu = ((nf + RT - 1) / RT) * 4;                 // units = token-batches x 4 quarters
  for (int u = blockIdx.x; u < nu; u += gridDim.x) {
    int fi0 = (u >> 2) * RT;
    int qq = u & 3;
    #pragma unroll
    for (int tt = 0; tt < 2; tt++) {
      int ts = wid * 2 + tt;
      int fi = fi0 + ts;
      if (fi < nf) {
        int token = flagList[fi];
        double s = 0.0;
        #pragma unroll
        for (int it = 0; it < 2; it++) {
          int e4 = lane + it * 64;
          float4 v = *(const float4*)(x + (size_t)token * DDIM + e4 * 4);
          double vx = (double)v.x, vy = (double)v.y, vz = (double)v.z, vw = (double)v.w;
          xd[ts][e4 * 4 + 0] = vx;
          xd[ts][e4 * 4 + 1] = vy;
          xd[ts][e4 * 4 + 2] = vz;
          xd[ts][e4 * 4 + 3] = vw;
          s += vx * vx + vy * vy + vz * vz + vw * vw;
        }
        for (int o = 32; o > 0; o >>= 1) s += __shfl_down(s, o, 64);
        if (lane == 0) a32[ts] = (float)s;
      } else {
        #pragma unroll
        for (int it = 0; it < 2; it++) {
          int e4 = lane + it * 64;
          xd[ts][e4 * 4 + 0] = 0.0; xd[ts][e4 * 4 + 1] = 0.0;
          xd[ts][e4 * 4 + 2] = 0.0; xd[ts][e4 * 4 + 3] = 0.0;
        }
        if (lane == 0) a32[ts] = 0.f;
      }
    }
    __syncthreads();

    unsigned long long key[RT];
    #pragma unroll
    for (int t = 0; t < RT; t++) key[t] = ~0ull;
    int k = qq * 256 + tid;
    if (k != 0) {
      const float4* wr = (const float4*)(w + (size_t)k * DDIM);
      double dacc[RT];
      #pragma unroll
      for (int t = 0; t < RT; t++) dacc[t] = 0.0;
      float4 wv = wr[0];
      for (int dq = 0; dq < DDIM / 4; dq++) {
        float4 cv = wv;
        if (dq < DDIM / 4 - 1) wv = wr[dq + 1];
        double wx = (double)cv.x, wy = (double)cv.y, wz = (double)cv.z, ww2 = (double)cv.w;
        #pragma unroll
        for (int t = 0; t < RT; t++) {
          dacc[t] += xd[t][dq*4+0]*wx + xd[t][dq*4+1]*wy
                   + xd[t][dq*4+2]*wz + xd[t][dq*4+3]*ww2;
        }
      }
      float wnk = wn32[k];
      #pragma unroll
      for (int t = 0; t < RT; t++) {
        float M = (float)dacc[t];
        float AB = a32[t] + wnk;
        float dist = AB - 2.0f * M;
        key[t] = ((unsigned long long)ordf(dist) << 32) | (unsigned)k;
      }
    }

    #pragma unroll
    for (int t = 0; t < RT; t++) {
      unsigned long long kk = key[t];
      for (int o = 32; o > 0; o >>= 1) {
        unsigned long long ok = __shfl_down(kk, o, 64);
        if (ok < kk) kk = ok;
      }
      if (lane == 0) wred[wid][t] = kk;
    }
    __syncthreads();
    if (tid < RT) {
      int fi = fi0 + tid;
      if (fi < nf) {
        unsigned long long kk = wred[0][tid];
        if (wred[1][tid] < kk) kk = wred[1][tid];
        if (wred[2][tid] < kk) kk = wred[2][tid];
        if (wred[3][tid] < kk) kk = wred[3][tid];
        if (kk != ~0ull) atomicMin(&keyMin[fi], kk);
      }
    }
    __syncthreads();
  }
}

// ---------------- apply keyMin -> idx/counts, restore dw zeros ----------------
__global__ __launch_bounds__(256) void finalize_kernel(
    const int* __restrict__ flagList, const int* __restrict__ flagcnt,
    unsigned long long* __restrict__ keyMin,
    int* __restrict__ idx_i, int* __restrict__ counts_i)
{
  int fi = blockIdx.x * 256 + threadIdx.x;   // grid 128 -> all 32768 slots
  int nf = *flagcnt;
  if (fi < nf) {
    unsigned long long kk = keyMin[fi];
    int token = flagList[fi];
    int nw = (int)(kk & 0xffffffffu);
    int old = idx_i[token];
    if (nw != old) {
      idx_i[token] = nw;
      atomicSub(&counts_i[old], 1);
      atomicAdd(&counts_i[nw], 1);
    }
  }
  keyMin[fi] = 0ull;   // keyMin aliases the head of dw: restore zeros for dw_kernel
}

// ---------------- exclusive scan of counts ----------------
__global__ __launch_bounds__(1024) void scan_kernel(
    const int* __restrict__ counts_i, int* __restrict__ offsets, int* __restrict__ cursor)
{
  __shared__ int tmp[1024];
  int t = threadIdx.x;
  int c = counts_i[t];
  tmp[t] = c;
  __syncthreads();
  for (int off = 1; off < 1024; off <<= 1) {
    int v = (t >= off) ? tmp[t - off] : 0;
    __syncthreads();
    tmp[t] += v;
    __syncthreads();
  }
  int ex = tmp[t] - c;
  offsets[t] = ex;
  cursor[t] = ex;
}

// ---------------- scatter with LDS rank aggregation ----------------
__global__ __launch_bounds__(1024) void scatter_kernel(
    const int* __restrict__ idx_i, int* __restrict__ cursor, int* __restrict__ bucket)
{
  __shared__ int lh[KCODE];
  __shared__ int lb[KCODE];
  int tid = threadIdx.x;
  lh[tid] = 0;
  __syncthreads();
  int token = blockIdx.x * 1024 + tid;
  int id = idx_i[token];
  int r = atomicAdd(&lh[id], 1);
  __syncthreads();
  if (lh[tid] > 0) lb[tid] = atomicAdd(&cursor[tid], lh[tid]);
  __syncthreads();
  bucket[lb[id] + r] = token;
}

// ---------------- quantized output + out_idx + loss ----------------
__global__ __launch_bounds__(256) void quant_kernel(
    const float* __restrict__ x, const float* __restrict__ w,
    const int* __restrict__ idx_i,
    float* __restrict__ out_q, float* __restrict__ out_idx, float* __restrict__ losssum)
{
  __shared__ float sred[4];
  int tid = threadIdx.x;
  int qd = tid & 127, h = tid >> 7;
  float s = 0.f;
  #pragma unroll
  for (int i = 0; i < 8; i++) {
    int token = blockIdx.x * 16 + i * 2 + h;
    int idx = idx_i[token];
    float4 xv = *(const float4*)(x + (size_t)token * DDIM + qd * 4);
    float4 wv = *(const float4*)(w + (size_t)idx * DDIM + qd * 4);
    *(float4*)(out_q + (size_t)token * DDIM + qd * 4) = wv;
    if (qd == 0) out_idx[token] = (float)idx;
    float dx = wv.x - xv.x, dy = wv.y - xv.y, dz = wv.z - xv.z, dww = wv.w - xv.w;
    s += dx*dx + dy*dy + dz*dz + dww*dww;
  }
  for (int o = 32; o > 0; o >>= 1) s += __shfl_down(s, o, 64);
  int lane = tid & 63, wid = tid >> 6;
  if (lane == 0) sred[wid] = s;
  __syncthreads();
  if (tid == 0) atomicAdd(losssum, sred[0] + sred[1] + sred[2] + sred[3]);
}

// ---------------- dw: balanced contiguous bucket ranges, run-flush atomics ----------------
__global__ __launch_bounds__(128) void dw_kernel(
    const float* __restrict__ x, const int* __restrict__ bucket,
    const int* __restrict__ idx_i, float* __restrict__ dw)
{
  int b0 = blockIdx.x * 32;
  int t = threadIdx.x;
  int ent = bucket[b0 + (t & 31)];
  int eid = idx_i[ent];
  int tok0 = __shfl(ent, 0, 64);
  int cur  = __shfl(eid, 0, 64);
  float4 acc = make_float4(0.f, 0.f, 0.f, 0.f);
  float4 nv = *(const float4*)(x + (size_t)tok0 * DDIM + t * 4);
  for (int j = 0; j < 32; j++) {
    float4 v = nv;
    int id = __shfl(eid, j, 64);
    if (j < 31) {
      int tn = __shfl(ent, j + 1, 64);
      nv = *(const float4*)(x + (size_t)tn * DDIM + t * 4);
    }
    if (id != cur) {   // wave-uniform branch
      float* p = dw + (size_t)cur * DDIM + t * 4;
      atomicAdd(p + 0, acc.x); atomicAdd(p + 1, acc.y);
      atomicAdd(p + 2, acc.z); atomicAdd(p + 3, acc.w);
      acc = make_float4(0.f, 0.f, 0.f, 0.f);
      cur = id;
    }
    acc.x += v.x; acc.y += v.y; acc.z += v.z; acc.w += v.w;
  }
  float* p = dw + (size_t)cur * DDIM + t * 4;
  atomicAdd(p + 0, acc.x); atomicAdd(p + 1, acc.y);
  atomicAdd(p + 2, acc.z); atomicAdd(p + 3, acc.w);
}

// ---------------- cs / loss / perplexity ----------------
__global__ __launch_bounds__(1024) void stats_kernel(
    const int* __restrict__ counts_i, const float* __restrict__ ema_cs,
    const float* __restrict__ losssum,
    float* __restrict__ out_loss, float* __restrict__ out_perp,
    float* __restrict__ out_cs)
{
  __shared__ float sbuf[17];
  int k = threadIdx.x;
  float cnt = (float)counts_i[k];
  float csr = ema_cs[k] * DECAYF + (1.f - DECAYF) * cnt;
  float v = csr;
  for (int o = 32; o > 0; o >>= 1) v += __shfl_down(v, o, 64);
  int lane = k & 63, wid = k >> 6;
  if (lane == 0) sbuf[wid] = v;
  __syncthreads();
  if (k == 0) { float n = 0.f; for (int i = 0; i < 16; i++) n += sbuf[i]; sbuf[16] = n; }
  __syncthreads();
  float n = sbuf[16];
  out_cs[k] = (csr + EPSV) / (n + (float)KCODE * EPSV) * n;
  __syncthreads();
  float p = cnt / (float)N_TOK;
  v = p * logf(p + 1e-10f);
  for (int o = 32; o > 0; o >>= 1) v += __shfl_down(v, o, 64);
  if (lane == 0) sbuf[wid] = v;
  __syncthreads();
  if (k == 0) {
    float s = 0.f; for (int i = 0; i < 16; i++) s += sbuf[i];
    out_perp[0] = expf(-s);
    float nonpad = (float)(N_TOK - counts_i[0]);
    out_loss[0] = CCOST * losssum[0] / (nonpad * (float)DDIM);
  }
}

// ---------------- EMA update + new codebook ----------------
__global__ __launch_bounds__(256) void ema_kernel(
    const float* __restrict__ ema_w, const float* __restrict__ dw,
    const float* __restrict__ cs,
    float* __restrict__ out_ema, float* __restrict__ out_cb)
{
  int i = blockIdx.x * 256 + threadIdx.x;
  int e = i * 4;
  int k = e >> 9;
  float4 dv = *(const float4*)(dw + e);
  float4 ew = *(const float4*)(ema_w + e);
  float4 ne;
  ne.x = ew.x * DECAYF + (1.f - DECAYF) * dv.x;
  ne.y = ew.y * DECAYF + (1.f - DECAYF) * dv.y;
  ne.z = ew.z * DECAYF + (1.f - DECAYF) * dv.z;
  ne.w = ew.w * DECAYF + (1.f - DECAYF) * dv.w;
  *(float4*)(out_ema + e) = ne;
  float4 cb;
  if (k == 0) { cb.x = 0.f; cb.y = 0.f; cb.z = 0.f; cb.w = 0.f; }
  else {
    float csk = cs[k];
    cb.x = ne.x / csk; cb.y = ne.y / csk; cb.z = ne.z / csk; cb.w = ne.w / csk;
  }
  *(float4*)(out_cb + e) = cb;
}

extern "C" void kernel_launch(void* const* d_in, const int* in_sizes, int n_in,
                              void* d_out, int out_size, void* d_ws, size_t ws_size,
                              hipStream_t stream) {
  const float* x      = (const float*)d_in[0];
  const int*   mask   = (const int*)d_in[1];
  const float* w      = (const float*)d_in[2];
  const float* ema_cs = (const float*)d_in[3];
  const float* ema_w  = (const float*)d_in[4];
  float* out = (float*)d_out;

  float* out_q    = out;                  // 16777216  quantized_st
  float* out_idx  = out + 16777216;       // 32768     idx (as float)
  float* out_loss = out + 16809984;       // 1
  float* out_perp = out + 16809985;       // 1
  float* out_cs   = out + 16809986;       // 1024
  float* out_ema  = out + 16811010;       // 524288
  float* out_cb   = out + 17335298;       // 524288

  // xhi/xlo live in the (dead until quant) out_q region: 2 x 32 MB
  unsigned short* xhi = (unsigned short*)out_q;
  unsigned short* xlo = xhi + (size_t)N_TOK * DDIM;

  char* ws = (char*)d_ws;
  int*   counts_i = (int*)  (ws + 0);          // 4 KB   (zeroed)
  float* dw       = (float*)(ws + 4096);       // 2 MB   (zeroed)
  // keyMin aliases the first 256 KB of dw: memset 0xFF before use, finalize
  // restores zeros before dw_kernel consumes dw.
  unsigned long long* keyMin = (unsigned long long*)(ws + 4096);
  float* losssum  = (float*)(ws + 2101248);    // 4 B    (zeroed)
  int*   flagcnt  = (int*)  (ws + 2101252);    // 4 B    (zeroed)
  int*   flagcnt2 = (int*)  (ws + 2101256);    // 4 B    (zeroed)
  int*   offsets  = (int*)  (ws + 2101312);    // 4 KB
  int*   cursor   = (int*)  (ws + 2105408);    // 4 KB
  float* wn       = (float*)(ws + 2109504);    // 4 KB
  int*   idx_i    = (int*)  (ws + 2113600);    // 128 KB
  int*   bucket   = (int*)  (ws + 2244672);    // 128 KB
  unsigned short* whi = (unsigned short*)(ws + 2375744);   // 1 MB
  unsigned short* wlo = (unsigned short*)(ws + 3424320);   // 1 MB
  unsigned long long* k1buf = (unsigned long long*)(ws + 4472896);  // 4 MB
  unsigned long long* k2buf = (unsigned long long*)(ws + 8667200);  // 4 MB
  int*   flagList  = (int*) (ws + 12861504);   // 128 KB
  int*   flagList2 = (int*) (ws + 12992576);   // 128 KB -> total ~13.1 MB

  hipMemsetAsync(ws, 0, 2101260, stream);        // counts + dw + losssum + flagcnt + flagcnt2
  hipMemsetAsync(ws + 4096, 0xFF, 262144, stream); // keyMin = ~0ull (head of dw)
  convert_fused<<<16384 + 256, 256, 0, stream>>>(x, w, xhi, xlo, whi, wlo, wn);
  dist_mfma<<<(N_TOK / 128) * 8, 256, 0, stream>>>(xhi, whi, wn, k1buf, k2buf);
  combine_kernel<<<N_TOK / 1024, 1024, 0, stream>>>(k1buf, k2buf, mask, idx_i, flagList, flagcnt, counts_i);
  refine_mfma<<<(N_TOK / 128) * 8, 256, 0, stream>>>(xhi, xlo, whi, wlo, wn, flagList, flagcnt, k1buf, k2buf);
  combine2_kernel<<<N_TOK / 256, 256, 0, stream>>>(k1buf, k2buf, flagList, flagcnt, idx_i, counts_i, flagList2, flagcnt2);
  refine_kernel<<<2048, 256, 0, stream>>>(x, w, wn, flagList2, flagcnt2, keyMin);
  finalize_kernel<<<N_TOK / 256, 256, 0, stream>>>(flagList2, flagcnt2, keyMin, idx_i, counts_i);
  scan_kernel<<<1, 1024, 0, stream>>>(counts_i, offsets, cursor);
  scatter_kernel<<<N_TOK / 1024, 1024, 0, stream>>>(idx_i, cursor, bucket);
  quant_kernel<<<N_TOK / 16, 256, 0, stream>>>(x, w, idx_i, out_q, out_idx, losssum);
  dw_kernel<<<N_TOK / 32, 128, 0, stream>>>(x, bucket, idx_i, dw);
  stats_kernel<<<1, 1024, 0, stream>>>(counts_i, ema_cs, losssum, out_loss, out_perp, out_cs);
  ema_kernel<<<KCODE * DDIM / 4 / 256, 256, 0, stream>>>(ema_w, dw, out_cs, out_ema, out_cb);
}